// Round 2
// baseline (2663.357 us; speedup 1.0000x reference)
//
#include <hip/hip_runtime.h>
#include <hip/hip_bf16.h>

typedef unsigned int u32;

#define B_  8
#define C_  64
#define N_  1000
#define T_  24
#define R_  10
#define NT_ 24000   // N*T
#define CT_ 1536    // C*T
#define NC_ 64000   // N*Co

// ---- LDS tree reductions (exactly 256 threads) ----
__device__ __forceinline__ float blockSum256(float v, float* red) {
  red[threadIdx.x] = v; __syncthreads();
  #pragma unroll
  for (int s = 128; s > 0; s >>= 1) {
    if (threadIdx.x < s) red[threadIdx.x] += red[threadIdx.x + s];
    __syncthreads();
  }
  float r = red[0]; __syncthreads();
  return r;
}
__device__ __forceinline__ float blockMax256(float v, float* red) {
  red[threadIdx.x] = v; __syncthreads();
  #pragma unroll
  for (int s = 128; s > 0; s >>= 1) {
    if (threadIdx.x < s) red[threadIdx.x] = fmaxf(red[threadIdx.x], red[threadIdx.x + s]);
    __syncthreads();
  }
  float r = red[0]; __syncthreads();
  return r;
}

__device__ __forceinline__ void ld24f32(const float* p, float* v) {
  #pragma unroll
  for (int t = 0; t < 24; t += 4) {
    float4 f = *(const float4*)&p[t];
    v[t] = f.x; v[t+1] = f.y; v[t+2] = f.z; v[t+3] = f.w;
  }
}

// ---------- zero small buffers ----------
__global__ __launch_bounds__(256) void zerok(float* p, int n) {
  int i = blockIdx.x * 256 + threadIdx.x;
  if (i < n) p[i] = 0.f;
}

// ---------- stage 1: block channel attention ----------
// grid 512 (b*64+i), block 256
__global__ __launch_bounds__(256) void att0_s12(
    const float* __restrict__ x, const float* __restrict__ W1,
    const float* __restrict__ W2, float* __restrict__ s1, float* __restrict__ s2) {
  __shared__ float red[256];
  int bi = blockIdx.x;
  const float* row = x + (size_t)bi * NT_;
  float a1[R_], a2[R_];
  #pragma unroll
  for (int r = 0; r < R_; ++r) { a1[r] = 0.f; a2[r] = 0.f; }
  for (int k = threadIdx.x; k < NT_; k += 256) {
    float xv = row[k];
    const float* w1r = W1 + (size_t)k * R_;
    #pragma unroll
    for (int r = 0; r < R_; ++r) a1[r] += xv * w1r[r];
    #pragma unroll
    for (int r = 0; r < R_; ++r) a2[r] += xv * W2[(size_t)r * NT_ + k];
  }
  #pragma unroll
  for (int r = 0; r < R_; ++r) {
    float t1 = blockSum256(a1[r], red);
    float t2 = blockSum256(a2[r], red);
    if (threadIdx.x == 0) { s1[bi * R_ + r] = t1; s2[bi * R_ + r] = t2; }
  }
}

// grid 8, block 64: P[b][i][j] softmax over j
__global__ __launch_bounds__(64) void att0_softmax(
    const float* __restrict__ s1, const float* __restrict__ s2, float* __restrict__ P) {
  int b = blockIdx.x, i = threadIdx.x;
  float r1[R_];
  #pragma unroll
  for (int r = 0; r < R_; ++r) r1[r] = s1[(b * 64 + i) * R_ + r];
  const float scale = rsqrtf(24000.f);
  float row[64]; float m = -1e30f;
  for (int j = 0; j < 64; ++j) {
    const float* s2r = s2 + (size_t)(b * 64 + j) * R_;
    float d = 0.f;
    #pragma unroll
    for (int r = 0; r < R_; ++r) d += r1[r] * s2r[r];
    d *= scale; row[j] = d; m = fmaxf(m, d);
  }
  float s = 0.f;
  for (int j = 0; j < 64; ++j) { float e = __expf(row[j] - m); row[j] = e; s += e; }
  float inv = 1.f / s;
  for (int j = 0; j < 64; ++j) P[((size_t)b * 64 + i) * 64 + j] = row[j] * inv;
}

// grid 8000 (b*1000+n), block 256: x1_tr[b][n][i*24+t] = sum_j P[b,i,j]*x[b,j,n,t]
__global__ __launch_bounds__(256) void att0_apply(
    const float* __restrict__ x, const float* __restrict__ P, float* __restrict__ x1tr) {
  __shared__ float Ps[4096];
  __shared__ float xt[CT_];
  int b = blockIdx.x / N_, n = blockIdx.x % N_;
  for (int i = threadIdx.x; i < 4096; i += 256) Ps[i] = P[(size_t)b * 4096 + i];
  for (int i = threadIdx.x; i < CT_; i += 256) {
    int j = i / T_, t = i - j * T_;
    xt[i] = x[(size_t)(b * 64 + j) * NT_ + n * T_ + t];
  }
  __syncthreads();
  float* dst = x1tr + ((size_t)b * N_ + n) * CT_;
  for (int i = threadIdx.x; i < CT_; i += 256) {
    int ii = i / T_, t = i - ii * T_;
    float acc = 0.f;
    #pragma unroll 8
    for (int j = 0; j < 64; ++j) acc += Ps[ii * 64 + j] * xt[j * T_ + t];
    dst[i] = acc;
  }
}

// ---------- stage 2: gated GCN ----------
// grid 8000, block 256
__global__ __launch_bounds__(256) void gatt_s12(
    const float* __restrict__ xg, const float* __restrict__ W1,
    const float* __restrict__ W2, float* __restrict__ s1, float* __restrict__ s2) {
  __shared__ float red[256];
  int bn = blockIdx.x;
  const float* row = xg + (size_t)bn * CT_;
  float a1[R_], a2[R_];
  #pragma unroll
  for (int r = 0; r < R_; ++r) { a1[r] = 0.f; a2[r] = 0.f; }
  for (int k = threadIdx.x; k < CT_; k += 256) {
    float xv = row[k];
    const float* w1r = W1 + (size_t)k * R_;
    #pragma unroll
    for (int r = 0; r < R_; ++r) a1[r] += xv * w1r[r];
    #pragma unroll
    for (int r = 0; r < R_; ++r) a2[r] += xv * W2[(size_t)r * CT_ + k];
  }
  #pragma unroll
  for (int r = 0; r < R_; ++r) {
    float t1 = blockSum256(a1[r], red);
    float t2 = blockSum256(a2[r], red);
    if (threadIdx.x == 0) { s1[bn * R_ + r] = t1; s2[bn * R_ + r] = t2; }
  }
}

// grid 8000 (b*1000+n), block 256: Ag row = softmax(scores)*A_adj
__global__ __launch_bounds__(256) void gatt_scores(
    const float* __restrict__ s1, const float* __restrict__ s2,
    const float* __restrict__ Aadj, float* __restrict__ Ag) {
  __shared__ float p[N_];
  __shared__ float r1[R_];
  __shared__ float red[256];
  int b = blockIdx.x / N_, n = blockIdx.x % N_;
  if (threadIdx.x < R_) r1[threadIdx.x] = s1[((size_t)b * N_ + n) * R_ + threadIdx.x];
  __syncthreads();
  const float scale = rsqrtf(1536.f);
  float lmax = -1e30f;
  for (int m = threadIdx.x; m < N_; m += 256) {
    const float* s2r = s2 + ((size_t)b * N_ + m) * R_;
    float d = 0.f;
    #pragma unroll
    for (int r = 0; r < R_; ++r) d += r1[r] * s2r[r];
    d *= scale; p[m] = d; lmax = fmaxf(lmax, d);
  }
  float gmax = blockMax256(lmax, red);
  float lsum = 0.f;
  for (int m = threadIdx.x; m < N_; m += 256) {
    float e = __expf(p[m] - gmax); p[m] = e; lsum += e;
  }
  float gsum = blockSum256(lsum, red);
  float inv = 1.f / gsum;
  float* agr = Ag + ((size_t)b * N_ + n) * N_;
  const float* ar = Aadj + (size_t)n * N_;
  for (int m = threadIdx.x; m < N_; m += 256) agr[m] = p[m] * inv * ar[m];
}

// batched GEMM: g1[b] = Ag[b](1000x1000) @ x1tr[b](1000x1536)
// grid (24, 16, 8), block 256; 64x64 tile, BK=16, 4x4 per thread
__global__ __launch_bounds__(256) void gemm_g1(
    const float* __restrict__ Ag, const float* __restrict__ X, float* __restrict__ g1) {
  int b = blockIdx.z;
  const float* A = Ag + (size_t)b * N_ * N_;
  const float* Bm = X + (size_t)b * N_ * CT_;
  float* C = g1 + (size_t)b * N_ * CT_;
  int bn = blockIdx.x * 64;   // col base (0..1472)
  int bm = blockIdx.y * 64;   // row base (0..960)
  __shared__ float As[16][68];
  __shared__ float Bs[16][68];
  int tx = threadIdx.x & 15, ty = threadIdx.x >> 4;
  float acc[4][4];
  #pragma unroll
  for (int i = 0; i < 4; ++i)
    #pragma unroll
    for (int j = 0; j < 4; ++j) acc[i][j] = 0.f;
  for (int k0 = 0; k0 < N_; k0 += 16) {
    for (int l = threadIdx.x; l < 1024; l += 256) {
      int m = l >> 4, kk = l & 15;
      int gm = bm + m, gk = k0 + kk;
      As[kk][m] = (gm < N_ && gk < N_) ? A[(size_t)gm * N_ + gk] : 0.f;
    }
    for (int l = threadIdx.x; l < 1024; l += 256) {
      int kk = l >> 6, nn = l & 63;
      int gk = k0 + kk;
      Bs[kk][nn] = (gk < N_) ? Bm[(size_t)gk * CT_ + bn + nn] : 0.f;
    }
    __syncthreads();
    #pragma unroll
    for (int kk = 0; kk < 16; ++kk) {
      float4 a4 = *(const float4*)&As[kk][ty * 4];
      float4 b4 = *(const float4*)&Bs[kk][tx * 4];
      float av[4] = {a4.x, a4.y, a4.z, a4.w};
      float bv[4] = {b4.x, b4.y, b4.z, b4.w};
      #pragma unroll
      for (int i = 0; i < 4; ++i)
        #pragma unroll
        for (int j = 0; j < 4; ++j) acc[i][j] += av[i] * bv[j];
    }
    __syncthreads();
  }
  #pragma unroll
  for (int i = 0; i < 4; ++i) {
    int gm = bm + ty * 4 + i;
    if (gm < N_) {
      float4 v = make_float4(acc[i][0], acc[i][1], acc[i][2], acc[i][3]);
      *(float4*)&C[(size_t)gm * CT_ + bn + tx * 4] = v;
    }
  }
}

// grid 8000 (b*1000+n), block 256: g[b,o,n,t] = sum_c g1[b,n,c,t]*W[c,o]
__global__ __launch_bounds__(256) void gcn_out(
    const float* __restrict__ g1, const float* __restrict__ W, float* __restrict__ g) {
  __shared__ float gs[CT_];
  __shared__ float Ws[4096];
  int b = blockIdx.x / N_, n = blockIdx.x % N_;
  const float* src = g1 + ((size_t)b * N_ + n) * CT_;
  for (int i = threadIdx.x; i < CT_; i += 256) gs[i] = src[i];
  for (int i = threadIdx.x; i < 4096; i += 256) Ws[i] = W[i];
  __syncthreads();
  for (int i = threadIdx.x; i < CT_; i += 256) {
    int o = i / T_, t = i - o * T_;
    float acc = 0.f;
    #pragma unroll 16
    for (int c = 0; c < 64; ++c) acc += gs[c * T_ + t] * Ws[c * 64 + o];
    g[(((size_t)b * C_ + o) * N_ + n) * T_ + t] = acc;
  }
}

// ---------- stage 3: temporal attention ----------
// grid (10, 24, 8) chunked over k2=n*64+o, block 256, atomic accumulate
__global__ __launch_bounds__(256) void tatt_s12(
    const float* __restrict__ g, const float* __restrict__ W1,
    const float* __restrict__ W2, float* __restrict__ s1, float* __restrict__ s2) {
  __shared__ float red[256];
  int chunk = blockIdx.x, t = blockIdx.y, b = blockIdx.z;
  int k0 = chunk * 6400;
  float a1[R_], a2[R_];
  #pragma unroll
  for (int r = 0; r < R_; ++r) { a1[r] = 0.f; a2[r] = 0.f; }
  for (int k = k0 + threadIdx.x; k < k0 + 6400; k += 256) {
    int n = k >> 6, o = k & 63;
    float xv = g[(((size_t)b * C_ + o) * N_ + n) * T_ + t];
    const float* w1r = W1 + (size_t)k * R_;
    #pragma unroll
    for (int r = 0; r < R_; ++r) a1[r] += xv * w1r[r];
    #pragma unroll
    for (int r = 0; r < R_; ++r) a2[r] += xv * W2[(size_t)r * NC_ + k];
  }
  #pragma unroll
  for (int r = 0; r < R_; ++r) {
    float t1 = blockSum256(a1[r], red);
    float t2 = blockSum256(a2[r], red);
    if (threadIdx.x == 0) {
      atomicAdd(&s1[(b * T_ + t) * R_ + r], t1);
      atomicAdd(&s2[(b * T_ + t) * R_ + r], t2);
    }
  }
}

// grid 8, block 32 (24 active): Pt[b][t][j]
__global__ __launch_bounds__(64) void tatt_softmax(
    const float* __restrict__ s1, const float* __restrict__ s2, float* __restrict__ Pt) {
  int b = blockIdx.x, t = threadIdx.x;
  if (t >= T_) return;
  float r1[R_];
  #pragma unroll
  for (int r = 0; r < R_; ++r) r1[r] = s1[(b * T_ + t) * R_ + r];
  const float scale = rsqrtf(64000.f);
  float row[T_]; float m = -1e30f;
  for (int j = 0; j < T_; ++j) {
    const float* s2r = s2 + (b * T_ + j) * R_;
    float d = 0.f;
    #pragma unroll
    for (int r = 0; r < R_; ++r) d += r1[r] * s2r[r];
    d *= scale; row[j] = d; m = fmaxf(m, d);
  }
  float s = 0.f;
  for (int j = 0; j < T_; ++j) { float e = __expf(row[j] - m); row[j] = e; s += e; }
  float inv = 1.f / s;
  for (int j = 0; j < T_; ++j) Pt[(b * T_ + t) * T_ + j] = row[j] * inv;
}

// grid (250, 8), block 256: x2[b,o,n,t] = sum_j Pt[b,t,j]*g[b,o,n,j]
__global__ __launch_bounds__(256) void tatt_apply(
    const float* __restrict__ g, const float* __restrict__ Pt, float* __restrict__ x2) {
  __shared__ float P[576];
  int b = blockIdx.y;
  for (int i = threadIdx.x; i < 576; i += 256) P[i] = Pt[b * 576 + i];
  __syncthreads();
  int row = blockIdx.x * 256 + threadIdx.x;           // 0..63999
  const float* gp = g + ((size_t)b * 64000 + row) * T_;
  float gr[T_];
  ld24f32(gp, gr);
  float out[T_];
  #pragma unroll
  for (int t = 0; t < T_; ++t) {
    float a = 0.f;
    const float* Pr = &P[t * T_];
    #pragma unroll
    for (int j = 0; j < T_; ++j) a += Pr[j] * gr[j];
    out[t] = a;
  }
  float* xp = x2 + ((size_t)b * 64000 + row) * T_;
  #pragma unroll
  for (int t = 0; t < T_; t += 4)
    *(float4*)&xp[t] = make_float4(out[t], out[t+1], out[t+2], out[t+3]);
}

// ---------- stage 4: dilated causal convs + residual + LN ----------
// grid 2000, block 256: thread per (b,o,n), dilation 1, relu
__global__ __launch_bounds__(256) void conv1_k(
    const float* __restrict__ in, const float* __restrict__ w,
    const float* __restrict__ bias, float* __restrict__ out) {
  int idx = blockIdx.x * 256 + threadIdx.x;
  int n = idx % N_; int q = idx / N_; int o = q & 63; int b = q >> 6;
  const float* xb = in + ((size_t)b * C_ * N_ + n) * T_;
  float acc[T_];
  float bz = bias[o];
  #pragma unroll
  for (int t = 0; t < T_; ++t) acc[t] = bz;
  for (int c = 0; c < C_; ++c) {
    float xv[T_];
    ld24f32(xb + (size_t)c * (N_ * T_), xv);
    float w0 = w[(o * 64 + c) * 2], w1 = w[(o * 64 + c) * 2 + 1];
    #pragma unroll
    for (int t = 0; t < T_; ++t) acc[t] += w1 * xv[t];
    #pragma unroll
    for (int t = 1; t < T_; ++t) acc[t] += w0 * xv[t - 1];
  }
  float* op = out + ((size_t)(b * C_ + o) * N_ + n) * T_;
  #pragma unroll
  for (int t = 0; t < T_; t += 4)
    *(float4*)&op[t] = make_float4(fmaxf(acc[t], 0.f), fmaxf(acc[t+1], 0.f),
                                   fmaxf(acc[t+2], 0.f), fmaxf(acc[t+3], 0.f));
}

// grid 2000, block 256: conv2 (dil 2, relu) + 1x1 residual, relu(sum) -> pre-LN
__global__ __launch_bounds__(256) void conv2res_k(
    const float* __restrict__ y1, const float* __restrict__ x,
    const float* __restrict__ w2, const float* __restrict__ bias2,
    const float* __restrict__ rw, const float* __restrict__ rb,
    float* __restrict__ out) {
  int idx = blockIdx.x * 256 + threadIdx.x;
  int n = idx % N_; int q = idx / N_; int o = q & 63; int b = q >> 6;
  const float* yb = y1 + ((size_t)b * C_ * N_ + n) * T_;
  const float* xb = x + ((size_t)b * C_ * N_ + n) * T_;
  float acc2[T_], accr[T_];
  float bz2 = bias2[o], bzr = rb[o];
  #pragma unroll
  for (int t = 0; t < T_; ++t) { acc2[t] = bz2; accr[t] = bzr; }
  for (int c = 0; c < C_; ++c) {
    float yv[T_], xv[T_];
    ld24f32(yb + (size_t)c * (N_ * T_), yv);
    ld24f32(xb + (size_t)c * (N_ * T_), xv);
    float w0 = w2[(o * 64 + c) * 2], w1v = w2[(o * 64 + c) * 2 + 1];
    float wr = rw[o * 64 + c];
    #pragma unroll
    for (int t = 0; t < T_; ++t) acc2[t] += w1v * yv[t];
    #pragma unroll
    for (int t = 2; t < T_; ++t) acc2[t] += w0 * yv[t - 2];
    #pragma unroll
    for (int t = 0; t < T_; ++t) accr[t] += wr * xv[t];
  }
  float* op = out + ((size_t)(b * C_ + o) * N_ + n) * T_;
  #pragma unroll
  for (int t = 0; t < T_; t += 4) {
    float v0 = fmaxf(fmaxf(acc2[t],   0.f) + accr[t],   0.f);
    float v1 = fmaxf(fmaxf(acc2[t+1], 0.f) + accr[t+1], 0.f);
    float v2 = fmaxf(fmaxf(acc2[t+2], 0.f) + accr[t+2], 0.f);
    float v3 = fmaxf(fmaxf(acc2[t+3], 0.f) + accr[t+3], 0.f);
    *(float4*)&op[t] = make_float4(v0, v1, v2, v3);
  }
}

// grid 8000 (b*1000+n), block 64: LayerNorm over channel dim (f32 out)
__global__ __launch_bounds__(64) void ln_k(
    const float* __restrict__ pre, const float* __restrict__ lg,
    const float* __restrict__ lb, float* __restrict__ outp) {
  __shared__ float vs[64][25];
  __shared__ float mu[T_], rstd[T_];
  int b = blockIdx.x / N_, n = blockIdx.x % N_;
  int o = threadIdx.x;
  const float* pr = pre + ((size_t)(b * C_ + o) * N_ + n) * T_;
  float v[T_];
  ld24f32(pr, v);
  #pragma unroll
  for (int t = 0; t < T_; ++t) vs[o][t] = v[t];
  __syncthreads();
  if (o < T_) {
    float s = 0.f;
    for (int c = 0; c < 64; ++c) s += vs[c][o];
    float m = s * (1.f / 64.f);
    float qq = 0.f;
    for (int c = 0; c < 64; ++c) { float d = vs[c][o] - m; qq += d * d; }
    mu[o] = m;
    rstd[o] = rsqrtf(qq * (1.f / 64.f) + 1e-5f);
  }
  __syncthreads();
  float go = lg[o], bo = lb[o];
  float w[T_];
  #pragma unroll
  for (int t = 0; t < T_; ++t) w[t] = (v[t] - mu[t]) * rstd[t] * go + bo;
  float* op = outp + ((size_t)(b * C_ + o) * N_ + n) * T_;
  #pragma unroll
  for (int t = 0; t < T_; t += 4)
    *(float4*)&op[t] = make_float4(w[t], w[t+1], w[t+2], w[t+3]);
}

extern "C" void kernel_launch(void* const* d_in, const int* in_sizes, int n_in,
                              void* d_out, int out_size, void* d_ws, size_t ws_size,
                              hipStream_t stream) {
  const float* x     = (const float*)d_in[0];
  const float* Aadj  = (const float*)d_in[1];
  const float* a0W1  = (const float*)d_in[2];
  const float* a0W2  = (const float*)d_in[3];
  const float* gW1   = (const float*)d_in[4];
  const float* gW2   = (const float*)d_in[5];
  const float* gcnW  = (const float*)d_in[6];
  const float* tW1   = (const float*)d_in[7];
  const float* tW2   = (const float*)d_in[8];
  const float* c1w   = (const float*)d_in[9];
  const float* c1b   = (const float*)d_in[10];
  const float* c2w   = (const float*)d_in[11];
  const float* c2b   = (const float*)d_in[12];
  const float* rw    = (const float*)d_in[13];
  const float* rb    = (const float*)d_in[14];
  const float* lng   = (const float*)d_in[15];
  const float* lnb   = (const float*)d_in[16];
  float* out = (float*)d_out;

  float* ws = (float*)d_ws;
  float* R1   = ws;                    // 12,288,000  x1_tr -> x2
  float* R2   = R1 + 12288000;         //  8,000,000  Ag
  float* R3   = R2 + 8000000;          // 12,288,000  g1 -> y1
  float* R4   = R3 + 12288000;         // 12,288,000  g_std -> preLN
  float* s1_0 = R4 + 12288000;         // 5120
  float* s2_0 = s1_0 + 5120;           // 5120
  float* P0   = s2_0 + 5120;           // 32768
  float* s1g  = P0 + 32768;            // 80000
  float* s2g  = s1g + 80000;           // 80000
  float* s1t  = s2g + 80000;           // 1920
  float* s2t  = s1t + 1920;            // 1920 (contiguous with s1t)
  float* Ptb  = s2t + 1920;            // 4608
  if (ws_size < (size_t)(45075456) * 4) return;  // workspace too small -> fail visibly

  // stage 1: channel attention
  att0_s12<<<512, 256, 0, stream>>>(x, a0W1, a0W2, s1_0, s2_0);
  att0_softmax<<<8, 64, 0, stream>>>(s1_0, s2_0, P0);
  att0_apply<<<8000, 256, 0, stream>>>(x, P0, R1);
  // stage 2: gated GCN
  gatt_s12<<<8000, 256, 0, stream>>>(R1, gW1, gW2, s1g, s2g);
  gatt_scores<<<8000, 256, 0, stream>>>(s1g, s2g, Aadj, R2);
  gemm_g1<<<dim3(24, 16, 8), 256, 0, stream>>>(R2, R1, R3);
  gcn_out<<<8000, 256, 0, stream>>>(R3, gcnW, R4);
  // stage 3: temporal attention
  zerok<<<15, 256, 0, stream>>>(s1t, 3840);
  tatt_s12<<<dim3(10, 24, 8), 256, 0, stream>>>(R4, tW1, tW2, s1t, s2t);
  tatt_softmax<<<8, 32, 0, stream>>>(s1t, s2t, Ptb);
  tatt_apply<<<dim3(250, 8), 256, 0, stream>>>(R4, Ptb, R1);
  // stage 4: TCN tail + residual + LN
  conv1_k<<<2000, 256, 0, stream>>>(R1, c1w, c1b, R3);
  conv2res_k<<<2000, 256, 0, stream>>>(R3, x, c2w, c2b, rw, rb, R4);
  ln_k<<<8000, 64, 0, stream>>>(R4, lng, lnb, out);
}

// Round 3
// 1260.550 us; speedup vs baseline: 2.1129x; 2.1129x over previous
//
#include <hip/hip_runtime.h>
#include <hip/hip_bf16.h>

typedef unsigned int u32;

#define B_  8
#define C_  64
#define N_  1000
#define T_  24
#define R_  10
#define NT_ 24000   // N*T
#define CT_ 1536    // C*T
#define NC_ 64000   // N*Co

// ---- LDS tree reductions (exactly 256 threads) ----
__device__ __forceinline__ float blockSum256(float v, float* red) {
  red[threadIdx.x] = v; __syncthreads();
  #pragma unroll
  for (int s = 128; s > 0; s >>= 1) {
    if (threadIdx.x < s) red[threadIdx.x] += red[threadIdx.x + s];
    __syncthreads();
  }
  float r = red[0]; __syncthreads();
  return r;
}
__device__ __forceinline__ float blockMax256(float v, float* red) {
  red[threadIdx.x] = v; __syncthreads();
  #pragma unroll
  for (int s = 128; s > 0; s >>= 1) {
    if (threadIdx.x < s) red[threadIdx.x] = fmaxf(red[threadIdx.x], red[threadIdx.x + s]);
    __syncthreads();
  }
  float r = red[0]; __syncthreads();
  return r;
}

__device__ __forceinline__ void ld24f32(const float* p, float* v) {
  #pragma unroll
  for (int t = 0; t < 24; t += 4) {
    float4 f = *(const float4*)&p[t];
    v[t] = f.x; v[t+1] = f.y; v[t+2] = f.z; v[t+3] = f.w;
  }
}

// ---------- zero small buffers ----------
__global__ __launch_bounds__(256) void zerok(float* p, int n) {
  int i = blockIdx.x * 256 + threadIdx.x;
  if (i < n) p[i] = 0.f;
}

// ---------- stage 1: block channel attention ----------
// grid 512 (b*64+i), block 256
__global__ __launch_bounds__(256) void att0_s12(
    const float* __restrict__ x, const float* __restrict__ W1,
    const float* __restrict__ W2, float* __restrict__ s1, float* __restrict__ s2) {
  __shared__ float red[256];
  int bi = blockIdx.x;
  const float* row = x + (size_t)bi * NT_;
  float a1[R_], a2[R_];
  #pragma unroll
  for (int r = 0; r < R_; ++r) { a1[r] = 0.f; a2[r] = 0.f; }
  for (int k = threadIdx.x; k < NT_; k += 256) {
    float xv = row[k];
    const float* w1r = W1 + (size_t)k * R_;
    #pragma unroll
    for (int r = 0; r < R_; ++r) a1[r] += xv * w1r[r];
    #pragma unroll
    for (int r = 0; r < R_; ++r) a2[r] += xv * W2[(size_t)r * NT_ + k];
  }
  #pragma unroll
  for (int r = 0; r < R_; ++r) {
    float t1 = blockSum256(a1[r], red);
    float t2 = blockSum256(a2[r], red);
    if (threadIdx.x == 0) { s1[bi * R_ + r] = t1; s2[bi * R_ + r] = t2; }
  }
}

// grid 8, block 64: P[b][i][j] softmax over j
__global__ __launch_bounds__(64) void att0_softmax(
    const float* __restrict__ s1, const float* __restrict__ s2, float* __restrict__ P) {
  int b = blockIdx.x, i = threadIdx.x;
  float r1[R_];
  #pragma unroll
  for (int r = 0; r < R_; ++r) r1[r] = s1[(b * 64 + i) * R_ + r];
  const float scale = rsqrtf(24000.f);
  float row[64]; float m = -1e30f;
  for (int j = 0; j < 64; ++j) {
    const float* s2r = s2 + (size_t)(b * 64 + j) * R_;
    float d = 0.f;
    #pragma unroll
    for (int r = 0; r < R_; ++r) d += r1[r] * s2r[r];
    d *= scale; row[j] = d; m = fmaxf(m, d);
  }
  float s = 0.f;
  for (int j = 0; j < 64; ++j) { float e = __expf(row[j] - m); row[j] = e; s += e; }
  float inv = 1.f / s;
  for (int j = 0; j < 64; ++j) P[((size_t)b * 64 + i) * 64 + j] = row[j] * inv;
}

// grid 8000 (b*1000+n), block 256: x1_tr[b][n][i*24+t] = sum_j P[b,i,j]*x[b,j,n,t]
__global__ __launch_bounds__(256) void att0_apply(
    const float* __restrict__ x, const float* __restrict__ P, float* __restrict__ x1tr) {
  __shared__ float Ps[4096];
  __shared__ float xt[CT_];
  int b = blockIdx.x / N_, n = blockIdx.x % N_;
  for (int i = threadIdx.x; i < 4096; i += 256) Ps[i] = P[(size_t)b * 4096 + i];
  for (int i = threadIdx.x; i < CT_; i += 256) {
    int j = i / T_, t = i - j * T_;
    xt[i] = x[(size_t)(b * 64 + j) * NT_ + n * T_ + t];
  }
  __syncthreads();
  float* dst = x1tr + ((size_t)b * N_ + n) * CT_;
  for (int i = threadIdx.x; i < CT_; i += 256) {
    int ii = i / T_, t = i - ii * T_;
    float acc = 0.f;
    #pragma unroll 8
    for (int j = 0; j < 64; ++j) acc += Ps[ii * 64 + j] * xt[j * T_ + t];
    dst[i] = acc;
  }
}

// ---------- stage 2: gated GCN ----------
// grid 8000, block 256
__global__ __launch_bounds__(256) void gatt_s12(
    const float* __restrict__ xg, const float* __restrict__ W1,
    const float* __restrict__ W2, float* __restrict__ s1, float* __restrict__ s2) {
  __shared__ float red[256];
  int bn = blockIdx.x;
  const float* row = xg + (size_t)bn * CT_;
  float a1[R_], a2[R_];
  #pragma unroll
  for (int r = 0; r < R_; ++r) { a1[r] = 0.f; a2[r] = 0.f; }
  for (int k = threadIdx.x; k < CT_; k += 256) {
    float xv = row[k];
    const float* w1r = W1 + (size_t)k * R_;
    #pragma unroll
    for (int r = 0; r < R_; ++r) a1[r] += xv * w1r[r];
    #pragma unroll
    for (int r = 0; r < R_; ++r) a2[r] += xv * W2[(size_t)r * CT_ + k];
  }
  #pragma unroll
  for (int r = 0; r < R_; ++r) {
    float t1 = blockSum256(a1[r], red);
    float t2 = blockSum256(a2[r], red);
    if (threadIdx.x == 0) { s1[bn * R_ + r] = t1; s2[bn * R_ + r] = t2; }
  }
}

// grid 8000 (b*1000+n), block 256: Ag row = softmax(scores)*A_adj
__global__ __launch_bounds__(256) void gatt_scores(
    const float* __restrict__ s1, const float* __restrict__ s2,
    const float* __restrict__ Aadj, float* __restrict__ Ag) {
  __shared__ float p[N_];
  __shared__ float r1[R_];
  __shared__ float red[256];
  int b = blockIdx.x / N_, n = blockIdx.x % N_;
  if (threadIdx.x < R_) r1[threadIdx.x] = s1[((size_t)b * N_ + n) * R_ + threadIdx.x];
  __syncthreads();
  const float scale = rsqrtf(1536.f);
  float lmax = -1e30f;
  for (int m = threadIdx.x; m < N_; m += 256) {
    const float* s2r = s2 + ((size_t)b * N_ + m) * R_;
    float d = 0.f;
    #pragma unroll
    for (int r = 0; r < R_; ++r) d += r1[r] * s2r[r];
    d *= scale; p[m] = d; lmax = fmaxf(lmax, d);
  }
  float gmax = blockMax256(lmax, red);
  float lsum = 0.f;
  for (int m = threadIdx.x; m < N_; m += 256) {
    float e = __expf(p[m] - gmax); p[m] = e; lsum += e;
  }
  float gsum = blockSum256(lsum, red);
  float inv = 1.f / gsum;
  float* agr = Ag + ((size_t)b * N_ + n) * N_;
  const float* ar = Aadj + (size_t)n * N_;
  for (int m = threadIdx.x; m < N_; m += 256) agr[m] = p[m] * inv * ar[m];
}

// batched GEMM: g1[b] = Ag[b](1000x1000) @ x1tr[b](1000x1536)
// grid (24, 16, 8), block 256; 64x64 tile, BK=16, 4x4 per thread
__global__ __launch_bounds__(256) void gemm_g1(
    const float* __restrict__ Ag, const float* __restrict__ X, float* __restrict__ g1) {
  int b = blockIdx.z;
  const float* A = Ag + (size_t)b * N_ * N_;
  const float* Bm = X + (size_t)b * N_ * CT_;
  float* C = g1 + (size_t)b * N_ * CT_;
  int bn = blockIdx.x * 64;   // col base (0..1472)
  int bm = blockIdx.y * 64;   // row base (0..960)
  __shared__ float As[16][68];
  __shared__ float Bs[16][68];
  int tx = threadIdx.x & 15, ty = threadIdx.x >> 4;
  float acc[4][4];
  #pragma unroll
  for (int i = 0; i < 4; ++i)
    #pragma unroll
    for (int j = 0; j < 4; ++j) acc[i][j] = 0.f;
  for (int k0 = 0; k0 < N_; k0 += 16) {
    for (int l = threadIdx.x; l < 1024; l += 256) {
      int m = l >> 4, kk = l & 15;
      int gm = bm + m, gk = k0 + kk;
      As[kk][m] = (gm < N_ && gk < N_) ? A[(size_t)gm * N_ + gk] : 0.f;
    }
    for (int l = threadIdx.x; l < 1024; l += 256) {
      int kk = l >> 6, nn = l & 63;
      int gk = k0 + kk;
      Bs[kk][nn] = (gk < N_) ? Bm[(size_t)gk * CT_ + bn + nn] : 0.f;
    }
    __syncthreads();
    #pragma unroll
    for (int kk = 0; kk < 16; ++kk) {
      float4 a4 = *(const float4*)&As[kk][ty * 4];
      float4 b4 = *(const float4*)&Bs[kk][tx * 4];
      float av[4] = {a4.x, a4.y, a4.z, a4.w};
      float bv[4] = {b4.x, b4.y, b4.z, b4.w};
      #pragma unroll
      for (int i = 0; i < 4; ++i)
        #pragma unroll
        for (int j = 0; j < 4; ++j) acc[i][j] += av[i] * bv[j];
    }
    __syncthreads();
  }
  #pragma unroll
  for (int i = 0; i < 4; ++i) {
    int gm = bm + ty * 4 + i;
    if (gm < N_) {
      float4 v = make_float4(acc[i][0], acc[i][1], acc[i][2], acc[i][3]);
      *(float4*)&C[(size_t)gm * CT_ + bn + tx * 4] = v;
    }
  }
}

// grid 8000 (b*1000+n), block 256: g[b,o,n,t] = sum_c g1[b,n,c,t]*W[c,o]
__global__ __launch_bounds__(256) void gcn_out(
    const float* __restrict__ g1, const float* __restrict__ W, float* __restrict__ g) {
  __shared__ float gs[CT_];
  __shared__ float Ws[4096];
  int b = blockIdx.x / N_, n = blockIdx.x % N_;
  const float* src = g1 + ((size_t)b * N_ + n) * CT_;
  for (int i = threadIdx.x; i < CT_; i += 256) gs[i] = src[i];
  for (int i = threadIdx.x; i < 4096; i += 256) Ws[i] = W[i];
  __syncthreads();
  for (int i = threadIdx.x; i < CT_; i += 256) {
    int o = i / T_, t = i - o * T_;
    float acc = 0.f;
    #pragma unroll 16
    for (int c = 0; c < 64; ++c) acc += gs[c * T_ + t] * Ws[c * 64 + o];
    g[(((size_t)b * C_ + o) * N_ + n) * T_ + t] = acc;
  }
}

// ---------- stage 3: temporal attention ----------
// grid (10, 24, 8) chunked over k2=n*64+o, block 256, atomic accumulate
__global__ __launch_bounds__(256) void tatt_s12(
    const float* __restrict__ g, const float* __restrict__ W1,
    const float* __restrict__ W2, float* __restrict__ s1, float* __restrict__ s2) {
  __shared__ float red[256];
  int chunk = blockIdx.x, t = blockIdx.y, b = blockIdx.z;
  int k0 = chunk * 6400;
  float a1[R_], a2[R_];
  #pragma unroll
  for (int r = 0; r < R_; ++r) { a1[r] = 0.f; a2[r] = 0.f; }
  for (int k = k0 + threadIdx.x; k < k0 + 6400; k += 256) {
    int n = k >> 6, o = k & 63;
    float xv = g[(((size_t)b * C_ + o) * N_ + n) * T_ + t];
    const float* w1r = W1 + (size_t)k * R_;
    #pragma unroll
    for (int r = 0; r < R_; ++r) a1[r] += xv * w1r[r];
    #pragma unroll
    for (int r = 0; r < R_; ++r) a2[r] += xv * W2[(size_t)r * NC_ + k];
  }
  #pragma unroll
  for (int r = 0; r < R_; ++r) {
    float t1 = blockSum256(a1[r], red);
    float t2 = blockSum256(a2[r], red);
    if (threadIdx.x == 0) {
      atomicAdd(&s1[(b * T_ + t) * R_ + r], t1);
      atomicAdd(&s2[(b * T_ + t) * R_ + r], t2);
    }
  }
}

// grid 8, block 32 (24 active): Pt[b][t][j]
__global__ __launch_bounds__(64) void tatt_softmax(
    const float* __restrict__ s1, const float* __restrict__ s2, float* __restrict__ Pt) {
  int b = blockIdx.x, t = threadIdx.x;
  if (t >= T_) return;
  float r1[R_];
  #pragma unroll
  for (int r = 0; r < R_; ++r) r1[r] = s1[(b * T_ + t) * R_ + r];
  const float scale = rsqrtf(64000.f);
  float row[T_]; float m = -1e30f;
  for (int j = 0; j < T_; ++j) {
    const float* s2r = s2 + (b * T_ + j) * R_;
    float d = 0.f;
    #pragma unroll
    for (int r = 0; r < R_; ++r) d += r1[r] * s2r[r];
    d *= scale; row[j] = d; m = fmaxf(m, d);
  }
  float s = 0.f;
  for (int j = 0; j < T_; ++j) { float e = __expf(row[j] - m); row[j] = e; s += e; }
  float inv = 1.f / s;
  for (int j = 0; j < T_; ++j) Pt[(b * T_ + t) * T_ + j] = row[j] * inv;
}

// grid (250, 8), block 256: x2[b,o,n,t] = sum_j Pt[b,t,j]*g[b,o,n,j]
__global__ __launch_bounds__(256) void tatt_apply(
    const float* __restrict__ g, const float* __restrict__ Pt, float* __restrict__ x2) {
  __shared__ float P[576];
  int b = blockIdx.y;
  for (int i = threadIdx.x; i < 576; i += 256) P[i] = Pt[b * 576 + i];
  __syncthreads();
  int row = blockIdx.x * 256 + threadIdx.x;           // 0..63999
  const float* gp = g + ((size_t)b * 64000 + row) * T_;
  float gr[T_];
  ld24f32(gp, gr);
  float out[T_];
  #pragma unroll
  for (int t = 0; t < T_; ++t) {
    float a = 0.f;
    const float* Pr = &P[t * T_];
    #pragma unroll
    for (int j = 0; j < T_; ++j) a += Pr[j] * gr[j];
    out[t] = a;
  }
  float* xp = x2 + ((size_t)b * 64000 + row) * T_;
  #pragma unroll
  for (int t = 0; t < T_; t += 4)
    *(float4*)&xp[t] = make_float4(out[t], out[t+1], out[t+2], out[t+3]);
}

// ---------- stage 4 (FUSED): conv1+relu -> conv2+relu + 1x1 res + relu -> LN ----------
// grid (250, 8), block 256: one block = 4 nodes x all 64 out-channels.
// Tiles for 4 nodes staged in LDS once => 64x channel-reuse happens in LDS,
// killing the 5x HBM over-fetch the split kernels had.
__global__ __launch_bounds__(256) void tail_k(
    const float* __restrict__ x2, const float* __restrict__ x,
    const float* __restrict__ c1w, const float* __restrict__ c1b,
    const float* __restrict__ c2w, const float* __restrict__ c2b,
    const float* __restrict__ rw, const float* __restrict__ rb,
    const float* __restrict__ lg, const float* __restrict__ lb,
    float* __restrict__ outp) {
  __shared__ float xs2[6144];   // [(c*4+ln)*24+t]  conv1 input, later pre-LN values
  __shared__ float xs [6144];   // residual input tile
  __shared__ float ys [6144];   // conv1 output tile
  __shared__ float mu[96], rs[96];
  int b = blockIdx.y, n0 = blockIdx.x * 4;
  int tid = threadIdx.x;
  int o = tid >> 2, ln = tid & 3;

  // stage x2-tile and x-tile: per channel c, 96 contiguous floats at ((b*64+c)*1000+n0)*24
  {
    const float4* s2 = (const float4*)(x2 + ((size_t)b * 64000 + n0) * 24);
    const float4* sx = (const float4*)(x  + ((size_t)b * 64000 + n0) * 24);
    float4* d2 = (float4*)xs2; float4* dx = (float4*)xs;
    for (int i = tid; i < 1536; i += 256) {
      int c = i / 24, j = i - c * 24;            // j in float4 units
      d2[i] = s2[(size_t)c * 6000 + j];
      dx[i] = sx[(size_t)c * 6000 + j];
    }
  }
  __syncthreads();

  float acc[24];
  // ---- conv1 (dilation 1, causal) + relu -> ys ----
  {
    float bz = c1b[o];
    #pragma unroll
    for (int t = 0; t < 24; ++t) acc[t] = bz;
    for (int c = 0; c < 64; ++c) {
      float v[24];
      ld24f32(&xs2[(c * 4 + ln) * 24], v);
      float2 w = *(const float2*)&c1w[(o * 64 + c) * 2];
      acc[0] += w.y * v[0];
      #pragma unroll
      for (int t = 1; t < 24; ++t) acc[t] += w.y * v[t] + w.x * v[t - 1];
    }
    float* yr = &ys[tid * 24];
    #pragma unroll
    for (int t = 0; t < 24; t += 4)
      *(float4*)&yr[t] = make_float4(fmaxf(acc[t], 0.f), fmaxf(acc[t+1], 0.f),
                                     fmaxf(acc[t+2], 0.f), fmaxf(acc[t+3], 0.f));
  }
  __syncthreads();

  // ---- conv2 (dilation 2, causal) + relu, + 1x1 residual, relu(sum) ----
  {
    float bz2 = c2b[o], bzr = rb[o];
    float a2[24], ar[24];
    #pragma unroll
    for (int t = 0; t < 24; ++t) { a2[t] = bz2; ar[t] = bzr; }
    for (int c = 0; c < 64; ++c) {
      float yv[24], xv[24];
      ld24f32(&ys[(c * 4 + ln) * 24], yv);
      ld24f32(&xs[(c * 4 + ln) * 24], xv);
      float2 w = *(const float2*)&c2w[(o * 64 + c) * 2];
      float wr = rw[o * 64 + c];
      #pragma unroll
      for (int t = 0; t < 24; ++t) a2[t] += w.y * yv[t];
      #pragma unroll
      for (int t = 2; t < 24; ++t) a2[t] += w.x * yv[t - 2];
      #pragma unroll
      for (int t = 0; t < 24; ++t) ar[t] += wr * xv[t];
    }
    #pragma unroll
    for (int t = 0; t < 24; ++t)
      acc[t] = fmaxf(fmaxf(a2[t], 0.f) + ar[t], 0.f);   // pre-LN value
  }
  __syncthreads();   // done reading xs2 as input; reuse it for pre-LN tile
  {
    float* pr = &xs2[tid * 24];
    #pragma unroll
    for (int t = 0; t < 24; t += 4)
      *(float4*)&pr[t] = make_float4(acc[t], acc[t+1], acc[t+2], acc[t+3]);
  }
  __syncthreads();

  // ---- LN stats over channel dim (64) for each of 96 (ln,t) pairs ----
  if (tid < 96) {
    float s = 0.f, q = 0.f;
    for (int c = 0; c < 64; ++c) {
      float v = xs2[c * 96 + tid];               // lanes read consecutive addrs
      s += v; q += v * v;
    }
    float m = s * (1.f / 64.f);
    float var = q * (1.f / 64.f) - m * m;
    mu[tid] = m;
    rs[tid] = rsqrtf(var + 1e-5f);
  }
  __syncthreads();

  // ---- normalize + affine + store ----
  {
    float go = lg[o], bo = lb[o];
    float w[24];
    #pragma unroll
    for (int t = 0; t < 24; ++t)
      w[t] = (acc[t] - mu[ln * 24 + t]) * rs[ln * 24 + t] * go + bo;
    float* op = outp + (((size_t)(b * 64 + o)) * 1000 + n0 + ln) * 24;
    #pragma unroll
    for (int t = 0; t < 24; t += 4)
      *(float4*)&op[t] = make_float4(w[t], w[t+1], w[t+2], w[t+3]);
  }
}

extern "C" void kernel_launch(void* const* d_in, const int* in_sizes, int n_in,
                              void* d_out, int out_size, void* d_ws, size_t ws_size,
                              hipStream_t stream) {
  const float* x     = (const float*)d_in[0];
  const float* Aadj  = (const float*)d_in[1];
  const float* a0W1  = (const float*)d_in[2];
  const float* a0W2  = (const float*)d_in[3];
  const float* gW1   = (const float*)d_in[4];
  const float* gW2   = (const float*)d_in[5];
  const float* gcnW  = (const float*)d_in[6];
  const float* tW1   = (const float*)d_in[7];
  const float* tW2   = (const float*)d_in[8];
  const float* c1w   = (const float*)d_in[9];
  const float* c1b   = (const float*)d_in[10];
  const float* c2w   = (const float*)d_in[11];
  const float* c2b   = (const float*)d_in[12];
  const float* rw    = (const float*)d_in[13];
  const float* rb    = (const float*)d_in[14];
  const float* lng   = (const float*)d_in[15];
  const float* lnb   = (const float*)d_in[16];
  float* out = (float*)d_out;

  float* ws = (float*)d_ws;
  float* R1   = ws;                    // 12,288,000  x1_tr -> x2
  float* R2   = R1 + 12288000;         //  8,000,000  Ag
  float* R3   = R2 + 8000000;          // 12,288,000  g1
  float* R4   = R3 + 12288000;         // 12,288,000  g_std
  float* s1_0 = R4 + 12288000;         // 5120
  float* s2_0 = s1_0 + 5120;           // 5120
  float* P0   = s2_0 + 5120;           // 32768
  float* s1g  = P0 + 32768;            // 80000
  float* s2g  = s1g + 80000;           // 80000
  float* s1t  = s2g + 80000;           // 1920
  float* s2t  = s1t + 1920;            // 1920 (contiguous with s1t)
  float* Ptb  = s2t + 1920;            // 4608
  if (ws_size < (size_t)(45075456) * 4) return;  // workspace too small -> fail visibly

  // stage 1: channel attention
  att0_s12<<<512, 256, 0, stream>>>(x, a0W1, a0W2, s1_0, s2_0);
  att0_softmax<<<8, 64, 0, stream>>>(s1_0, s2_0, P0);
  att0_apply<<<8000, 256, 0, stream>>>(x, P0, R1);
  // stage 2: gated GCN
  gatt_s12<<<8000, 256, 0, stream>>>(R1, gW1, gW2, s1g, s2g);
  gatt_scores<<<8000, 256, 0, stream>>>(s1g, s2g, Aadj, R2);
  gemm_g1<<<dim3(24, 16, 8), 256, 0, stream>>>(R2, R1, R3);
  gcn_out<<<8000, 256, 0, stream>>>(R3, gcnW, R4);
  // stage 3: temporal attention
  zerok<<<15, 256, 0, stream>>>(s1t, 3840);
  tatt_s12<<<dim3(10, 24, 8), 256, 0, stream>>>(R4, tW1, tW2, s1t, s2t);
  tatt_softmax<<<8, 32, 0, stream>>>(s1t, s2t, Ptb);
  tatt_apply<<<dim3(250, 8), 256, 0, stream>>>(R4, Ptb, R1);
  // stage 4: fused TCN tail + residual + LN
  tail_k<<<dim3(250, 8), 256, 0, stream>>>(R1, x, c1w, c1b, c2w, c2b,
                                           rw, rb, lng, lnb, out);
}

// Round 4
// 899.125 us; speedup vs baseline: 2.9622x; 1.4020x over previous
//
#include <hip/hip_runtime.h>
#include <hip/hip_bf16.h>

typedef unsigned int u32;
typedef unsigned short ushortt;

#define B_  8
#define C_  64
#define N_  1000
#define T_  24
#define R_  10
#define NT_ 24000   // N*T
#define CT_ 1536    // C*T
#define NC_ 64000   // N*Co

typedef __attribute__((ext_vector_type(8))) short bf8v;
typedef __attribute__((ext_vector_type(4))) float f4v;

__device__ __forceinline__ ushortt f2b_bits(float f) {
  u32 x = __float_as_uint(f);
  u32 r = (x + 0x7fffu + ((x >> 16) & 1u)) >> 16;   // round-to-nearest-even
  return (ushortt)r;
}

// ---- LDS tree reductions (exactly 256 threads) ----
__device__ __forceinline__ float blockSum256(float v, float* red) {
  red[threadIdx.x] = v; __syncthreads();
  #pragma unroll
  for (int s = 128; s > 0; s >>= 1) {
    if (threadIdx.x < s) red[threadIdx.x] += red[threadIdx.x + s];
    __syncthreads();
  }
  float r = red[0]; __syncthreads();
  return r;
}
__device__ __forceinline__ float blockMax256(float v, float* red) {
  red[threadIdx.x] = v; __syncthreads();
  #pragma unroll
  for (int s = 128; s > 0; s >>= 1) {
    if (threadIdx.x < s) red[threadIdx.x] = fmaxf(red[threadIdx.x], red[threadIdx.x + s]);
    __syncthreads();
  }
  float r = red[0]; __syncthreads();
  return r;
}

__device__ __forceinline__ void ld24f32(const float* p, float* v) {
  #pragma unroll
  for (int t = 0; t < 24; t += 4) {
    float4 f = *(const float4*)&p[t];
    v[t] = f.x; v[t+1] = f.y; v[t+2] = f.z; v[t+3] = f.w;
  }
}

// ---------- zero small buffers ----------
__global__ __launch_bounds__(256) void zerok(float* p, int n) {
  int i = blockIdx.x * 256 + threadIdx.x;
  if (i < n) p[i] = 0.f;
}

// ---------- stage 1: block channel attention ----------
__global__ __launch_bounds__(256) void att0_s12(
    const float* __restrict__ x, const float* __restrict__ W1,
    const float* __restrict__ W2, float* __restrict__ s1, float* __restrict__ s2) {
  __shared__ float red[256];
  int bi = blockIdx.x;
  const float* row = x + (size_t)bi * NT_;
  float a1[R_], a2[R_];
  #pragma unroll
  for (int r = 0; r < R_; ++r) { a1[r] = 0.f; a2[r] = 0.f; }
  for (int k = threadIdx.x; k < NT_; k += 256) {
    float xv = row[k];
    const float* w1r = W1 + (size_t)k * R_;
    #pragma unroll
    for (int r = 0; r < R_; ++r) a1[r] += xv * w1r[r];
    #pragma unroll
    for (int r = 0; r < R_; ++r) a2[r] += xv * W2[(size_t)r * NT_ + k];
  }
  #pragma unroll
  for (int r = 0; r < R_; ++r) {
    float t1 = blockSum256(a1[r], red);
    float t2 = blockSum256(a2[r], red);
    if (threadIdx.x == 0) { s1[bi * R_ + r] = t1; s2[bi * R_ + r] = t2; }
  }
}

__global__ __launch_bounds__(64) void att0_softmax(
    const float* __restrict__ s1, const float* __restrict__ s2, float* __restrict__ P) {
  int b = blockIdx.x, i = threadIdx.x;
  float r1[R_];
  #pragma unroll
  for (int r = 0; r < R_; ++r) r1[r] = s1[(b * 64 + i) * R_ + r];
  const float scale = rsqrtf(24000.f);
  float row[64]; float m = -1e30f;
  for (int j = 0; j < 64; ++j) {
    const float* s2r = s2 + (size_t)(b * 64 + j) * R_;
    float d = 0.f;
    #pragma unroll
    for (int r = 0; r < R_; ++r) d += r1[r] * s2r[r];
    d *= scale; row[j] = d; m = fmaxf(m, d);
  }
  float s = 0.f;
  for (int j = 0; j < 64; ++j) { float e = __expf(row[j] - m); row[j] = e; s += e; }
  float inv = 1.f / s;
  for (int j = 0; j < 64; ++j) P[((size_t)b * 64 + i) * 64 + j] = row[j] * inv;
}

__global__ __launch_bounds__(256) void att0_apply(
    const float* __restrict__ x, const float* __restrict__ P, float* __restrict__ x1tr) {
  __shared__ float Ps[4096];
  __shared__ float xt[CT_];
  int b = blockIdx.x / N_, n = blockIdx.x % N_;
  for (int i = threadIdx.x; i < 4096; i += 256) Ps[i] = P[(size_t)b * 4096 + i];
  for (int i = threadIdx.x; i < CT_; i += 256) {
    int j = i / T_, t = i - j * T_;
    xt[i] = x[(size_t)(b * 64 + j) * NT_ + n * T_ + t];
  }
  __syncthreads();
  float* dst = x1tr + ((size_t)b * N_ + n) * CT_;
  for (int i = threadIdx.x; i < CT_; i += 256) {
    int ii = i / T_, t = i - ii * T_;
    float acc = 0.f;
    #pragma unroll 8
    for (int j = 0; j < 64; ++j) acc += Ps[ii * 64 + j] * xt[j * T_ + t];
    dst[i] = acc;
  }
}

// ---------- transpose x1tr [b][n][ct] f32 -> Xbt [b][ct][n pad 1024] bf16 ----------
// grid (24, 16, 8), block 256
__global__ __launch_bounds__(256) void transpose_x1(
    const float* __restrict__ x1tr, ushortt* __restrict__ Xbt) {
  __shared__ float s[64][65];
  int b = blockIdx.z, n0 = blockIdx.y * 64, c0 = blockIdx.x * 64;
  int tid = threadIdx.x;
  int r = tid >> 2, cc = (tid & 3) * 16;
  if (n0 + r < N_) {
    const float* src = x1tr + ((size_t)b * N_ + n0 + r) * CT_ + c0 + cc;
    #pragma unroll
    for (int i = 0; i < 16; i += 4) {
      float4 v = *(const float4*)&src[i];
      s[r][cc + i] = v.x; s[r][cc + i + 1] = v.y;
      s[r][cc + i + 2] = v.z; s[r][cc + i + 3] = v.w;
    }
  } else {
    #pragma unroll
    for (int i = 0; i < 16; ++i) s[r][cc + i] = 0.f;
  }
  __syncthreads();
  ushortt* dst = Xbt + ((size_t)b * CT_ + c0 + r) * 1024 + n0 + cc;
  #pragma unroll
  for (int i = 0; i < 16; ++i) dst[i] = f2b_bits(s[cc + i][r]);
}

// ---------- stage 2: gated GCN ----------
__global__ __launch_bounds__(256) void gatt_s12(
    const float* __restrict__ xg, const float* __restrict__ W1,
    const float* __restrict__ W2, float* __restrict__ s1, float* __restrict__ s2) {
  __shared__ float red[256];
  int bn = blockIdx.x;
  const float* row = xg + (size_t)bn * CT_;
  float a1[R_], a2[R_];
  #pragma unroll
  for (int r = 0; r < R_; ++r) { a1[r] = 0.f; a2[r] = 0.f; }
  for (int k = threadIdx.x; k < CT_; k += 256) {
    float xv = row[k];
    const float* w1r = W1 + (size_t)k * R_;
    #pragma unroll
    for (int r = 0; r < R_; ++r) a1[r] += xv * w1r[r];
    #pragma unroll
    for (int r = 0; r < R_; ++r) a2[r] += xv * W2[(size_t)r * CT_ + k];
  }
  #pragma unroll
  for (int r = 0; r < R_; ++r) {
    float t1 = blockSum256(a1[r], red);
    float t2 = blockSum256(a2[r], red);
    if (threadIdx.x == 0) { s1[bn * R_ + r] = t1; s2[bn * R_ + r] = t2; }
  }
}

// grid 8000 (b*1000+n), block 256: Agb row (bf16, K padded to 1024 with zeros)
__global__ __launch_bounds__(256) void gatt_scores(
    const float* __restrict__ s1, const float* __restrict__ s2,
    const float* __restrict__ Aadj, ushortt* __restrict__ Agb) {
  __shared__ float p[N_];
  __shared__ float r1[R_];
  __shared__ float red[256];
  int b = blockIdx.x / N_, n = blockIdx.x % N_;
  if (threadIdx.x < R_) r1[threadIdx.x] = s1[((size_t)b * N_ + n) * R_ + threadIdx.x];
  __syncthreads();
  const float scale = rsqrtf(1536.f);
  float lmax = -1e30f;
  for (int m = threadIdx.x; m < N_; m += 256) {
    const float* s2r = s2 + ((size_t)b * N_ + m) * R_;
    float d = 0.f;
    #pragma unroll
    for (int r = 0; r < R_; ++r) d += r1[r] * s2r[r];
    d *= scale; p[m] = d; lmax = fmaxf(lmax, d);
  }
  float gmax = blockMax256(lmax, red);
  float lsum = 0.f;
  for (int m = threadIdx.x; m < N_; m += 256) {
    float e = __expf(p[m] - gmax); p[m] = e; lsum += e;
  }
  float gsum = blockSum256(lsum, red);
  float inv = 1.f / gsum;
  ushortt* agr = Agb + ((size_t)b * 1024 + n) * 1024;
  const float* ar = Aadj + (size_t)n * N_;
  for (int m = threadIdx.x; m < 1024; m += 256) {
    float v = (m < N_) ? p[m] * inv * ar[m] : 0.f;
    agr[m] = f2b_bits(v);
  }
}

// ---------- batched MFMA GEMM: g1[b](1000x1536) = Agb[b](1024x1024) @ Xbt[b]^T ----------
// grid (12, 8, 8), block 256 (4 waves, 2x2 of 64x64), 128x128 tile, BK=32
__global__ __launch_bounds__(256) void gemm_mfma(
    const ushortt* __restrict__ Agb, const ushortt* __restrict__ Xbt,
    float* __restrict__ g1) {
  __shared__ ushortt As[4096];   // [m 0..127][k 0..31]
  __shared__ ushortt Bs[4096];   // [n 0..127][k 0..31]
  const int b = blockIdx.z;
  const int n0 = blockIdx.x * 128;
  const int m0 = blockIdx.y * 128;
  const ushortt* Ab = Agb + (size_t)b * 1024 * 1024;
  const ushortt* Bb = Xbt + (size_t)b * 1536 * 1024;
  const int tid = threadIdx.x;
  const int wave = tid >> 6, lane = tid & 63;
  const int wr = (wave >> 1) * 64, wc = (wave & 1) * 64;
  const int lrow = lane >> 2;          // 0..15
  const int lcol = (lane & 3) * 8;     // 0,8,16,24 (bf16 units)
  const int q = lane >> 4, l15 = lane & 15;

  f4v acc[4][4];
  #pragma unroll
  for (int i = 0; i < 4; ++i)
    #pragma unroll
    for (int j = 0; j < 4; ++j) acc[i][j] = (f4v){0.f, 0.f, 0.f, 0.f};

  // per-lane global pointers; LDS dest is wave-uniform base + lane*16B
  const ushortt* gA = Ab + (size_t)(m0 + wave * 16 + lrow) * 1024 + lcol;
  const ushortt* gB = Bb + (size_t)(n0 + wave * 16 + lrow) * 1024 + lcol;
  ushortt* lA = &As[wave * 16 * 32];
  ushortt* lB = &Bs[wave * 16 * 32];

  for (int k0 = 0; k0 < 1024; k0 += 32) {
    __syncthreads();
    __builtin_amdgcn_global_load_lds(
      (const __attribute__((address_space(1))) void*)(gA + k0),
      (__attribute__((address_space(3))) void*)lA, 16, 0, 0);
    __builtin_amdgcn_global_load_lds(
      (const __attribute__((address_space(1))) void*)(gA + (size_t)64 * 1024 + k0),
      (__attribute__((address_space(3))) void*)(lA + 64 * 32), 16, 0, 0);
    __builtin_amdgcn_global_load_lds(
      (const __attribute__((address_space(1))) void*)(gB + k0),
      (__attribute__((address_space(3))) void*)lB, 16, 0, 0);
    __builtin_amdgcn_global_load_lds(
      (const __attribute__((address_space(1))) void*)(gB + (size_t)64 * 1024 + k0),
      (__attribute__((address_space(3))) void*)(lB + 64 * 32), 16, 0, 0);
    __syncthreads();
    bf8v af[4], bfr[4];
    #pragma unroll
    for (int i = 0; i < 4; ++i)
      af[i] = *(const bf8v*)&As[(wr + i * 16 + l15) * 32 + q * 8];
    #pragma unroll
    for (int j = 0; j < 4; ++j)
      bfr[j] = *(const bf8v*)&Bs[(wc + j * 16 + l15) * 32 + q * 8];
    #pragma unroll
    for (int i = 0; i < 4; ++i)
      #pragma unroll
      for (int j = 0; j < 4; ++j)
        acc[i][j] = __builtin_amdgcn_mfma_f32_16x16x32_bf16(af[i], bfr[j], acc[i][j], 0, 0, 0);
  }
  // epilogue: D row = quad*4+reg, col = lane&15 (within each 16x16 tile)
  #pragma unroll
  for (int i = 0; i < 4; ++i) {
    int rbase = m0 + wr + i * 16 + q * 4;
    #pragma unroll
    for (int r = 0; r < 4; ++r) {
      int gm = rbase + r;
      if (gm < N_) {
        float* dst = g1 + ((size_t)b * N_ + gm) * CT_ + n0 + wc + l15;
        #pragma unroll
        for (int j = 0; j < 4; ++j) dst[j * 16] = acc[i][j][r];
      }
    }
  }
}

// grid 8000 (b*1000+n), block 256: g[b,o,n,t] = sum_c g1[b,n,c,t]*W[c,o]
__global__ __launch_bounds__(256) void gcn_out(
    const float* __restrict__ g1, const float* __restrict__ W, float* __restrict__ g) {
  __shared__ float gs[CT_];
  __shared__ float Ws[4096];
  int b = blockIdx.x / N_, n = blockIdx.x % N_;
  const float* src = g1 + ((size_t)b * N_ + n) * CT_;
  for (int i = threadIdx.x; i < CT_; i += 256) gs[i] = src[i];
  for (int i = threadIdx.x; i < 4096; i += 256) Ws[i] = W[i];
  __syncthreads();
  for (int i = threadIdx.x; i < CT_; i += 256) {
    int o = i / T_, t = i - o * T_;
    float acc = 0.f;
    #pragma unroll 16
    for (int c = 0; c < 64; ++c) acc += gs[c * T_ + t] * Ws[c * 64 + o];
    g[(((size_t)b * C_ + o) * N_ + n) * T_ + t] = acc;
  }
}

// ---------- stage 3: temporal attention ----------
__global__ __launch_bounds__(256) void tatt_s12(
    const float* __restrict__ g, const float* __restrict__ W1,
    const float* __restrict__ W2, float* __restrict__ s1, float* __restrict__ s2) {
  __shared__ float red[256];
  int chunk = blockIdx.x, t = blockIdx.y, b = blockIdx.z;
  int k0 = chunk * 6400;
  float a1[R_], a2[R_];
  #pragma unroll
  for (int r = 0; r < R_; ++r) { a1[r] = 0.f; a2[r] = 0.f; }
  for (int k = k0 + threadIdx.x; k < k0 + 6400; k += 256) {
    int n = k >> 6, o = k & 63;
    float xv = g[(((size_t)b * C_ + o) * N_ + n) * T_ + t];
    const float* w1r = W1 + (size_t)k * R_;
    #pragma unroll
    for (int r = 0; r < R_; ++r) a1[r] += xv * w1r[r];
    #pragma unroll
    for (int r = 0; r < R_; ++r) a2[r] += xv * W2[(size_t)r * NC_ + k];
  }
  #pragma unroll
  for (int r = 0; r < R_; ++r) {
    float t1 = blockSum256(a1[r], red);
    float t2 = blockSum256(a2[r], red);
    if (threadIdx.x == 0) {
      atomicAdd(&s1[(b * T_ + t) * R_ + r], t1);
      atomicAdd(&s2[(b * T_ + t) * R_ + r], t2);
    }
  }
}

__global__ __launch_bounds__(64) void tatt_softmax(
    const float* __restrict__ s1, const float* __restrict__ s2, float* __restrict__ Pt) {
  int b = blockIdx.x, t = threadIdx.x;
  if (t >= T_) return;
  float r1[R_];
  #pragma unroll
  for (int r = 0; r < R_; ++r) r1[r] = s1[(b * T_ + t) * R_ + r];
  const float scale = rsqrtf(64000.f);
  float row[T_]; float m = -1e30f;
  for (int j = 0; j < T_; ++j) {
    const float* s2r = s2 + (b * T_ + j) * R_;
    float d = 0.f;
    #pragma unroll
    for (int r = 0; r < R_; ++r) d += r1[r] * s2r[r];
    d *= scale; row[j] = d; m = fmaxf(m, d);
  }
  float s = 0.f;
  for (int j = 0; j < T_; ++j) { float e = __expf(row[j] - m); row[j] = e; s += e; }
  float inv = 1.f / s;
  for (int j = 0; j < T_; ++j) Pt[(b * T_ + t) * T_ + j] = row[j] * inv;
}

__global__ __launch_bounds__(256) void tatt_apply(
    const float* __restrict__ g, const float* __restrict__ Pt, float* __restrict__ x2) {
  __shared__ float P[576];
  int b = blockIdx.y;
  for (int i = threadIdx.x; i < 576; i += 256) P[i] = Pt[b * 576 + i];
  __syncthreads();
  int row = blockIdx.x * 256 + threadIdx.x;           // 0..63999
  const float* gp = g + ((size_t)b * 64000 + row) * T_;
  float gr[T_];
  ld24f32(gp, gr);
  float out[T_];
  #pragma unroll
  for (int t = 0; t < T_; ++t) {
    float a = 0.f;
    const float* Pr = &P[t * T_];
    #pragma unroll
    for (int j = 0; j < T_; ++j) a += Pr[j] * gr[j];
    out[t] = a;
  }
  float* xp = x2 + ((size_t)b * 64000 + row) * T_;
  #pragma unroll
  for (int t = 0; t < T_; t += 4)
    *(float4*)&xp[t] = make_float4(out[t], out[t+1], out[t+2], out[t+3]);
}

// ---------- stage 4 (FUSED): conv1+relu -> conv2+relu + 1x1 res + relu -> LN ----------
__global__ __launch_bounds__(256) void tail_k(
    const float* __restrict__ x2, const float* __restrict__ x,
    const float* __restrict__ c1w, const float* __restrict__ c1b,
    const float* __restrict__ c2w, const float* __restrict__ c2b,
    const float* __restrict__ rw, const float* __restrict__ rb,
    const float* __restrict__ lg, const float* __restrict__ lb,
    float* __restrict__ outp) {
  __shared__ float xs2[6144];
  __shared__ float xs [6144];
  __shared__ float ys [6144];
  __shared__ float mu[96], rs[96];
  int b = blockIdx.y, n0 = blockIdx.x * 4;
  int tid = threadIdx.x;
  int o = tid >> 2, ln = tid & 3;
  {
    const float4* s2 = (const float4*)(x2 + ((size_t)b * 64000 + n0) * 24);
    const float4* sx = (const float4*)(x  + ((size_t)b * 64000 + n0) * 24);
    float4* d2 = (float4*)xs2; float4* dx = (float4*)xs;
    for (int i = tid; i < 1536; i += 256) {
      int c = i / 24, j = i - c * 24;
      d2[i] = s2[(size_t)c * 6000 + j];
      dx[i] = sx[(size_t)c * 6000 + j];
    }
  }
  __syncthreads();
  float acc[24];
  {
    float bz = c1b[o];
    #pragma unroll
    for (int t = 0; t < 24; ++t) acc[t] = bz;
    for (int c = 0; c < 64; ++c) {
      float v[24];
      ld24f32(&xs2[(c * 4 + ln) * 24], v);
      float2 w = *(const float2*)&c1w[(o * 64 + c) * 2];
      acc[0] += w.y * v[0];
      #pragma unroll
      for (int t = 1; t < 24; ++t) acc[t] += w.y * v[t] + w.x * v[t - 1];
    }
    float* yr = &ys[tid * 24];
    #pragma unroll
    for (int t = 0; t < 24; t += 4)
      *(float4*)&yr[t] = make_float4(fmaxf(acc[t], 0.f), fmaxf(acc[t+1], 0.f),
                                     fmaxf(acc[t+2], 0.f), fmaxf(acc[t+3], 0.f));
  }
  __syncthreads();
  {
    float bz2 = c2b[o], bzr = rb[o];
    float a2[24], ar[24];
    #pragma unroll
    for (int t = 0; t < 24; ++t) { a2[t] = bz2; ar[t] = bzr; }
    for (int c = 0; c < 64; ++c) {
      float yv[24], xv[24];
      ld24f32(&ys[(c * 4 + ln) * 24], yv);
      ld24f32(&xs[(c * 4 + ln) * 24], xv);
      float2 w = *(const float2*)&c2w[(o * 64 + c) * 2];
      float wr = rw[o * 64 + c];
      #pragma unroll
      for (int t = 0; t < 24; ++t) a2[t] += w.y * yv[t];
      #pragma unroll
      for (int t = 2; t < 24; ++t) a2[t] += w.x * yv[t - 2];
      #pragma unroll
      for (int t = 0; t < 24; ++t) ar[t] += wr * xv[t];
    }
    #pragma unroll
    for (int t = 0; t < 24; ++t)
      acc[t] = fmaxf(fmaxf(a2[t], 0.f) + ar[t], 0.f);
  }
  __syncthreads();
  {
    float* pr = &xs2[tid * 24];
    #pragma unroll
    for (int t = 0; t < 24; t += 4)
      *(float4*)&pr[t] = make_float4(acc[t], acc[t+1], acc[t+2], acc[t+3]);
  }
  __syncthreads();
  if (tid < 96) {
    float s = 0.f, q = 0.f;
    for (int c = 0; c < 64; ++c) {
      float v = xs2[c * 96 + tid];
      s += v; q += v * v;
    }
    float m = s * (1.f / 64.f);
    float var = q * (1.f / 64.f) - m * m;
    mu[tid] = m;
    rs[tid] = rsqrtf(var + 1e-5f);
  }
  __syncthreads();
  {
    float go = lg[o], bo = lb[o];
    float w[24];
    #pragma unroll
    for (int t = 0; t < 24; ++t)
      w[t] = (acc[t] - mu[ln * 24 + t]) * rs[ln * 24 + t] * go + bo;
    float* op = outp + (((size_t)(b * 64 + o)) * 1000 + n0 + ln) * 24;
    #pragma unroll
    for (int t = 0; t < 24; t += 4)
      *(float4*)&op[t] = make_float4(w[t], w[t+1], w[t+2], w[t+3]);
  }
}

extern "C" void kernel_launch(void* const* d_in, const int* in_sizes, int n_in,
                              void* d_out, int out_size, void* d_ws, size_t ws_size,
                              hipStream_t stream) {
  const float* x     = (const float*)d_in[0];
  const float* Aadj  = (const float*)d_in[1];
  const float* a0W1  = (const float*)d_in[2];
  const float* a0W2  = (const float*)d_in[3];
  const float* gW1   = (const float*)d_in[4];
  const float* gW2   = (const float*)d_in[5];
  const float* gcnW  = (const float*)d_in[6];
  const float* tW1   = (const float*)d_in[7];
  const float* tW2   = (const float*)d_in[8];
  const float* c1w   = (const float*)d_in[9];
  const float* c1b   = (const float*)d_in[10];
  const float* c2w   = (const float*)d_in[11];
  const float* c2b   = (const float*)d_in[12];
  const float* rw    = (const float*)d_in[13];
  const float* rb    = (const float*)d_in[14];
  const float* lng   = (const float*)d_in[15];
  const float* lnb   = (const float*)d_in[16];
  float* out = (float*)d_out;

  float* ws = (float*)d_ws;
  float* R1   = ws;                    // 12,288,000 f: x1tr (f32), later x2
  float* U    = R1 + 12288000;         // 12,288,000 f union:
  //   Xbt bf16 [8][1536][1024] = 6,291,456 f-eq at U
  //   Agb bf16 [8][1024][1024] = 4,194,304 f-eq at U+6,291,456  (ends 10,485,760)
  //   later: g f32 [8,64,1000,24] = 12,288,000 f overlays whole U
  float* D    = U + 12288000;          // 12,288,000 f: g1
  float* s1_0 = D + 12288000;          // 5120
  float* s2_0 = s1_0 + 5120;           // 5120
  float* P0   = s2_0 + 5120;           // 32768
  float* s1g  = P0 + 32768;            // 80000
  float* s2g  = s1g + 80000;           // 80000
  float* s1t  = s2g + 80000;           // 1920
  float* s2t  = s1t + 1920;            // 1920
  float* Ptb  = s2t + 1920;            // 4608
  ushortt* Xbt = (ushortt*)U;
  ushortt* Agb = (ushortt*)(U + 6291456);
  float* g = U;
  if (ws_size < (size_t)37075456 * 4) return;  // fits in proven-available scratch

  // stage 1: channel attention
  att0_s12<<<512, 256, 0, stream>>>(x, a0W1, a0W2, s1_0, s2_0);
  att0_softmax<<<8, 64, 0, stream>>>(s1_0, s2_0, P0);
  att0_apply<<<8000, 256, 0, stream>>>(x, P0, R1);
  // stage 2: gated GCN
  gatt_s12<<<8000, 256, 0, stream>>>(R1, gW1, gW2, s1g, s2g);
  transpose_x1<<<dim3(24, 16, 8), 256, 0, stream>>>(R1, Xbt);
  gatt_scores<<<8000, 256, 0, stream>>>(s1g, s2g, Aadj, Agb);
  gemm_mfma<<<dim3(12, 8, 8), 256, 0, stream>>>(Agb, Xbt, D);
  gcn_out<<<8000, 256, 0, stream>>>(D, gcnW, g);
  // stage 3: temporal attention
  zerok<<<15, 256, 0, stream>>>(s1t, 3840);
  tatt_s12<<<dim3(10, 24, 8), 256, 0, stream>>>(g, tW1, tW2, s1t, s2t);
  tatt_softmax<<<8, 32, 0, stream>>>(s1t, s2t, Ptb);
  tatt_apply<<<dim3(250, 8), 256, 0, stream>>>(g, Ptb, R1);
  // stage 4: fused TCN tail + residual + LN
  tail_k<<<dim3(250, 8), 256, 0, stream>>>(R1, x, c1w, c1b, c2w, c2b,
                                           rw, rb, lng, lnb, out);
}

// Round 5
// 716.664 us; speedup vs baseline: 3.7163x; 1.2546x over previous
//
#include <hip/hip_runtime.h>
#include <hip/hip_bf16.h>

typedef unsigned int u32;
typedef unsigned short ushortt;

#define B_  8
#define C_  64
#define N_  1000
#define T_  24
#define R_  10
#define NT_ 24000   // N*T
#define CT_ 1536    // C*T
#define NC_ 64000   // N*Co

typedef __attribute__((ext_vector_type(8))) short bf8v;
typedef __attribute__((ext_vector_type(4))) float f4v;

__device__ __forceinline__ ushortt f2b_bits(float f) {
  u32 x = __float_as_uint(f);
  u32 r = (x + 0x7fffu + ((x >> 16) & 1u)) >> 16;   // round-to-nearest-even
  return (ushortt)r;
}

__device__ __forceinline__ float blockSum256(float v, float* red) {
  red[threadIdx.x] = v; __syncthreads();
  #pragma unroll
  for (int s = 128; s > 0; s >>= 1) {
    if (threadIdx.x < s) red[threadIdx.x] += red[threadIdx.x + s];
    __syncthreads();
  }
  float r = red[0]; __syncthreads();
  return r;
}
__device__ __forceinline__ float blockMax256(float v, float* red) {
  red[threadIdx.x] = v; __syncthreads();
  #pragma unroll
  for (int s = 128; s > 0; s >>= 1) {
    if (threadIdx.x < s) red[threadIdx.x] = fmaxf(red[threadIdx.x], red[threadIdx.x + s]);
    __syncthreads();
  }
  float r = red[0]; __syncthreads();
  return r;
}

__device__ __forceinline__ void ld24f32(const float* p, float* v) {
  #pragma unroll
  for (int t = 0; t < 24; t += 4) {
    float4 f = *(const float4*)&p[t];
    v[t] = f.x; v[t+1] = f.y; v[t+2] = f.z; v[t+3] = f.w;
  }
}

// ---------- utility ----------
__global__ __launch_bounds__(256) void zerok(float* p, int n) {
  int i = blockIdx.x * 256 + threadIdx.x;
  if (i < n) p[i] = 0.f;
}

// pack W1[K][10] and W2[10][K] -> Wp[K][20]
__global__ __launch_bounds__(256) void pack_w(
    const float* __restrict__ W1, const float* __restrict__ W2,
    float* __restrict__ Wp, int K) {
  int i = blockIdx.x * 256 + threadIdx.x;
  if (i >= K * 20) return;
  int k = i / 20, r = i - k * 20;
  Wp[i] = (r < 10) ? W1[(size_t)k * 10 + r] : W2[(size_t)(r - 10) * K + k];
}

// ---------- stage 1: channel attention scores ----------
// grid 256 (2 rows/block), block 256: rows = b*64+c (512 total), K=24000
__global__ __launch_bounds__(256) void att0_s12(
    const float* __restrict__ x, const float* __restrict__ Wp,
    float* __restrict__ s1, float* __restrict__ s2) {
  __shared__ float red[5120];
  int rid = threadIdx.x >> 7, ks = threadIdx.x & 127;
  int row = blockIdx.x * 2 + rid;
  const float* xr = x + (size_t)row * NT_;
  float a[20];
  #pragma unroll
  for (int r = 0; r < 20; ++r) a[r] = 0.f;
  for (int k = ks; k < NT_; k += 128) {
    float xv = xr[k];
    const float4* wp4 = (const float4*)&Wp[(size_t)k * 20];
    float4 wa = wp4[0], wb = wp4[1], wc = wp4[2], wd = wp4[3], we = wp4[4];
    float wv[20] = {wa.x,wa.y,wa.z,wa.w, wb.x,wb.y,wb.z,wb.w, wc.x,wc.y,wc.z,wc.w,
                    wd.x,wd.y,wd.z,wd.w, we.x,we.y,we.z,we.w};
    #pragma unroll
    for (int r = 0; r < 20; ++r) a[r] += xv * wv[r];
  }
  #pragma unroll
  for (int r = 0; r < 20; ++r) red[threadIdx.x * 20 + r] = a[r];
  __syncthreads();
  if (threadIdx.x < 40) {
    int rid2 = threadIdx.x / 20, r = threadIdx.x % 20;
    float s = 0.f;
    for (int l = 0; l < 128; ++l) s += red[(rid2 * 128 + l) * 20 + r];
    int orow = blockIdx.x * 2 + rid2;
    if (r < 10) s1[orow * 10 + r] = s;
    else        s2[orow * 10 + (r - 10)] = s;
  }
}

// grid 8, block 64: P[b][i][j] softmax over j
__global__ __launch_bounds__(64) void att0_softmax(
    const float* __restrict__ s1, const float* __restrict__ s2, float* __restrict__ P) {
  int b = blockIdx.x, i = threadIdx.x;
  float r1[R_];
  #pragma unroll
  for (int r = 0; r < R_; ++r) r1[r] = s1[(b * 64 + i) * R_ + r];
  const float scale = rsqrtf(24000.f);
  float row[64]; float m = -1e30f;
  for (int j = 0; j < 64; ++j) {
    const float* s2r = s2 + (size_t)(b * 64 + j) * R_;
    float d = 0.f;
    #pragma unroll
    for (int r = 0; r < R_; ++r) d += r1[r] * s2r[r];
    d *= scale; row[j] = d; m = fmaxf(m, d);
  }
  float s = 0.f;
  for (int j = 0; j < 64; ++j) { float e = __expf(row[j] - m); row[j] = e; s += e; }
  float inv = 1.f / s;
  for (int j = 0; j < 64; ++j) P[((size_t)b * 64 + i) * 64 + j] = row[j] * inv;
}

// grid (250, 8), block 256: x1tr[b][n][i*24+t] = sum_j P[b,i,j]*x[b,j,n,t]
// 4 nodes/block, thread = (ig 16, ln 4, ts 4) computing 4 i x 6 t
__global__ __launch_bounds__(256) void att0_apply(
    const float* __restrict__ x, const float* __restrict__ P, float* __restrict__ x1tr) {
  __shared__ float Pss[4160];   // [64][65] padded
  __shared__ float xt[6144];    // [j 64][ln 4][t 24]
  int b = blockIdx.y, n0 = blockIdx.x * 4;
  int tid = threadIdx.x;
  for (int i = tid; i < 4096; i += 256)
    Pss[(i >> 6) * 65 + (i & 63)] = P[(size_t)b * 4096 + i];
  {
    const float4* src4 = (const float4*)x;
    float4* dst4 = (float4*)xt;
    for (int i = tid; i < 1536; i += 256) {
      int j = i / 24, q = i - j * 24;
      dst4[i] = src4[(size_t)(b * 64 + j) * 6000 + n0 * 6 + q];
    }
  }
  __syncthreads();
  int ig = tid >> 4, ln = (tid >> 2) & 3, ts = tid & 3;
  float acc[4][6];
  #pragma unroll
  for (int ii = 0; ii < 4; ++ii)
    #pragma unroll
    for (int m = 0; m < 6; ++m) acc[ii][m] = 0.f;
  const float* base = &xt[ln * 24 + ts * 6];
  #pragma unroll 4
  for (int j = 0; j < 64; ++j) {
    float vj[6];
    #pragma unroll
    for (int m = 0; m < 6; ++m) vj[m] = base[j * 96 + m];
    #pragma unroll
    for (int ii = 0; ii < 4; ++ii) {
      float p = Pss[(ig * 4 + ii) * 65 + j];
      #pragma unroll
      for (int m = 0; m < 6; ++m) acc[ii][m] += p * vj[m];
    }
  }
  float* drow = x1tr + ((size_t)b * N_ + n0 + ln) * CT_ + ts * 6;
  #pragma unroll
  for (int ii = 0; ii < 4; ++ii) {
    float* d = drow + (ig * 4 + ii) * 24;
    *(float2*)&d[0] = make_float2(acc[ii][0], acc[ii][1]);
    *(float2*)&d[2] = make_float2(acc[ii][2], acc[ii][3]);
    *(float2*)&d[4] = make_float2(acc[ii][4], acc[ii][5]);
  }
}

// ---------- transpose x1tr [b][n][ct] f32 -> Xbt [b][ct][n pad 1024] bf16 ----------
__global__ __launch_bounds__(256) void transpose_x1(
    const float* __restrict__ x1tr, ushortt* __restrict__ Xbt) {
  __shared__ float s[64][65];
  int b = blockIdx.z, n0 = blockIdx.y * 64, c0 = blockIdx.x * 64;
  int tid = threadIdx.x;
  int r = tid >> 2, cc = (tid & 3) * 16;
  if (n0 + r < N_) {
    const float* src = x1tr + ((size_t)b * N_ + n0 + r) * CT_ + c0 + cc;
    #pragma unroll
    for (int i = 0; i < 16; i += 4) {
      float4 v = *(const float4*)&src[i];
      s[r][cc + i] = v.x; s[r][cc + i + 1] = v.y;
      s[r][cc + i + 2] = v.z; s[r][cc + i + 3] = v.w;
    }
  } else {
    #pragma unroll
    for (int i = 0; i < 16; ++i) s[r][cc + i] = 0.f;
  }
  __syncthreads();
  ushortt* dst = Xbt + ((size_t)b * CT_ + c0 + r) * 1024 + n0 + cc;
  #pragma unroll
  for (int i = 0; i < 16; ++i) dst[i] = f2b_bits(s[cc + i][r]);
}

// ---------- stage 2: gate scores ----------
// grid 2000 (4 rows/block), block 256: K=1536; writes s1 row-major, s2 transposed
__global__ __launch_bounds__(256) void gatt_s12(
    const float* __restrict__ xg, const float* __restrict__ Wp,
    float* __restrict__ s1, float* __restrict__ s2T) {
  __shared__ float xs[6144];
  __shared__ float red[5120];
  int bn0 = blockIdx.x * 4;
  int tid = threadIdx.x;
  {
    const float4* src4 = (const float4*)(xg + (size_t)bn0 * CT_);
    float4* dst4 = (float4*)xs;
    for (int i = tid; i < 1536; i += 256) dst4[i] = src4[i];
  }
  __syncthreads();
  int rid = tid >> 6, ks = tid & 63;
  float a[20];
  #pragma unroll
  for (int r = 0; r < 20; ++r) a[r] = 0.f;
  for (int k = ks; k < CT_; k += 64) {
    float xv = xs[rid * CT_ + k];
    const float4* wp4 = (const float4*)&Wp[(size_t)k * 20];
    float4 wa = wp4[0], wb = wp4[1], wc = wp4[2], wd = wp4[3], we = wp4[4];
    float wv[20] = {wa.x,wa.y,wa.z,wa.w, wb.x,wb.y,wb.z,wb.w, wc.x,wc.y,wc.z,wc.w,
                    wd.x,wd.y,wd.z,wd.w, we.x,we.y,we.z,we.w};
    #pragma unroll
    for (int r = 0; r < 20; ++r) a[r] += xv * wv[r];
  }
  #pragma unroll
  for (int r = 0; r < 20; ++r) red[tid * 20 + r] = a[r];
  __syncthreads();
  if (tid < 80) {
    int rid2 = tid / 20, r = tid % 20;
    float s = 0.f;
    for (int l = 0; l < 64; ++l) s += red[(rid2 * 64 + l) * 20 + r];
    int row = bn0 + rid2;
    int b = row / N_, n = row - b * N_;
    if (r < 10) s1[row * 10 + r] = s;
    else        s2T[((size_t)b * 10 + (r - 10)) * N_ + n] = s;
  }
}

// grid 8000, block 256: Agb row (bf16, K padded to 1024)
__global__ __launch_bounds__(256) void gatt_scores(
    const float* __restrict__ s1, const float* __restrict__ s2T,
    const float* __restrict__ Aadj, ushortt* __restrict__ Agb) {
  __shared__ float p[N_];
  __shared__ float r1[R_];
  __shared__ float red[256];
  int b = blockIdx.x / N_, n = blockIdx.x % N_;
  if (threadIdx.x < R_) r1[threadIdx.x] = s1[((size_t)b * N_ + n) * R_ + threadIdx.x];
  __syncthreads();
  const float scale = rsqrtf(1536.f);
  const float* s2b = s2T + (size_t)b * 10 * N_;
  float lmax = -1e30f;
  for (int m = threadIdx.x; m < N_; m += 256) {
    float d = 0.f;
    #pragma unroll
    for (int r = 0; r < R_; ++r) d += r1[r] * s2b[r * N_ + m];
    d *= scale; p[m] = d; lmax = fmaxf(lmax, d);
  }
  float gmax = blockMax256(lmax, red);
  float lsum = 0.f;
  for (int m = threadIdx.x; m < N_; m += 256) {
    float e = __expf(p[m] - gmax); p[m] = e; lsum += e;
  }
  float gsum = blockSum256(lsum, red);
  float inv = 1.f / gsum;
  ushortt* agr = Agb + ((size_t)b * 1024 + n) * 1024;
  const float* ar = Aadj + (size_t)n * N_;
  for (int m = threadIdx.x; m < 1024; m += 256) {
    float v = (m < N_) ? p[m] * inv * ar[m] : 0.f;
    agr[m] = f2b_bits(v);
  }
}

// ---------- batched MFMA GEMM: g1[b](1000x1536) = Agb[b](1024x1024) @ Xbt[b]^T ----------
__global__ __launch_bounds__(256) void gemm_mfma(
    const ushortt* __restrict__ Agb, const ushortt* __restrict__ Xbt,
    float* __restrict__ g1) {
  __shared__ ushortt As[4096];
  __shared__ ushortt Bs[4096];
  const int b = blockIdx.z;
  const int n0 = blockIdx.x * 128;
  const int m0 = blockIdx.y * 128;
  const ushortt* Ab = Agb + (size_t)b * 1024 * 1024;
  const ushortt* Bb = Xbt + (size_t)b * 1536 * 1024;
  const int tid = threadIdx.x;
  const int wave = tid >> 6, lane = tid & 63;
  const int wr = (wave >> 1) * 64, wc = (wave & 1) * 64;
  const int lrow = lane >> 2;
  const int lcol = (lane & 3) * 8;
  const int q = lane >> 4, l15 = lane & 15;

  f4v acc[4][4];
  #pragma unroll
  for (int i = 0; i < 4; ++i)
    #pragma unroll
    for (int j = 0; j < 4; ++j) acc[i][j] = (f4v){0.f, 0.f, 0.f, 0.f};

  const ushortt* gA = Ab + (size_t)(m0 + wave * 16 + lrow) * 1024 + lcol;
  const ushortt* gB = Bb + (size_t)(n0 + wave * 16 + lrow) * 1024 + lcol;
  ushortt* lA = &As[wave * 16 * 32];
  ushortt* lB = &Bs[wave * 16 * 32];

  for (int k0 = 0; k0 < 1024; k0 += 32) {
    __syncthreads();
    __builtin_amdgcn_global_load_lds(
      (const __attribute__((address_space(1))) void*)(gA + k0),
      (__attribute__((address_space(3))) void*)lA, 16, 0, 0);
    __builtin_amdgcn_global_load_lds(
      (const __attribute__((address_space(1))) void*)(gA + (size_t)64 * 1024 + k0),
      (__attribute__((address_space(3))) void*)(lA + 64 * 32), 16, 0, 0);
    __builtin_amdgcn_global_load_lds(
      (const __attribute__((address_space(1))) void*)(gB + k0),
      (__attribute__((address_space(3))) void*)lB, 16, 0, 0);
    __builtin_amdgcn_global_load_lds(
      (const __attribute__((address_space(1))) void*)(gB + (size_t)64 * 1024 + k0),
      (__attribute__((address_space(3))) void*)(lB + 64 * 32), 16, 0, 0);
    __syncthreads();
    bf8v af[4], bfr[4];
    #pragma unroll
    for (int i = 0; i < 4; ++i)
      af[i] = *(const bf8v*)&As[(wr + i * 16 + l15) * 32 + q * 8];
    #pragma unroll
    for (int j = 0; j < 4; ++j)
      bfr[j] = *(const bf8v*)&Bs[(wc + j * 16 + l15) * 32 + q * 8];
    #pragma unroll
    for (int i = 0; i < 4; ++i)
      #pragma unroll
      for (int j = 0; j < 4; ++j)
        acc[i][j] = __builtin_amdgcn_mfma_f32_16x16x32_bf16(af[i], bfr[j], acc[i][j], 0, 0, 0);
  }
  #pragma unroll
  for (int i = 0; i < 4; ++i) {
    int rbase = m0 + wr + i * 16 + q * 4;
    #pragma unroll
    for (int r = 0; r < 4; ++r) {
      int gm = rbase + r;
      if (gm < N_) {
        float* dst = g1 + ((size_t)b * N_ + gm) * CT_ + n0 + wc + l15;
        #pragma unroll
        for (int j = 0; j < 4; ++j) dst[j * 16] = acc[i][j][r];
      }
    }
  }
}

// grid (250, 8), block 256: g[b,o,n,t] = sum_c g1[b,n,c,t]*W[c,o]
// 4 nodes/block, thread = (og 16, ln 4, ts 4) computing 4 o x 6 t
__global__ __launch_bounds__(256) void gcn_out(
    const float* __restrict__ g1, const float* __restrict__ W, float* __restrict__ g) {
  __shared__ float gs[6160];    // [ln 4][1540 pad] of [c 64][t 24]
  __shared__ float Ws[4096];    // [c][o]
  int b = blockIdx.y, n0 = blockIdx.x * 4;
  int tid = threadIdx.x;
  {
    const float4* src4 = (const float4*)g1;
    float4* dst4 = (float4*)gs;
    for (int i = tid; i < 1536; i += 256) {
      int ln = i / 384, q = i - ln * 384;
      dst4[ln * 385 + q] = src4[(size_t)(b * N_ + n0 + ln) * 384 + q];
    }
  }
  for (int i = tid; i < 4096; i += 256) Ws[i] = W[i];
  __syncthreads();
  int og = tid >> 4, ln = (tid >> 2) & 3, ts = tid & 3;
  float acc[4][6];
  #pragma unroll
  for (int oo = 0; oo < 4; ++oo)
    #pragma unroll
    for (int m = 0; m < 6; ++m) acc[oo][m] = 0.f;
  const float* base = &gs[ln * 1540 + ts * 6];
  #pragma unroll 4
  for (int c = 0; c < 64; ++c) {
    float v[6];
    #pragma unroll
    for (int m = 0; m < 6; ++m) v[m] = base[c * 24 + m];
    float4 w4 = *(const float4*)&Ws[c * 64 + og * 4];
    float wv[4] = {w4.x, w4.y, w4.z, w4.w};
    #pragma unroll
    for (int oo = 0; oo < 4; ++oo)
      #pragma unroll
      for (int m = 0; m < 6; ++m) acc[oo][m] += wv[oo] * v[m];
  }
  #pragma unroll
  for (int oo = 0; oo < 4; ++oo) {
    int o = og * 4 + oo;
    float* d = g + (((size_t)(b * C_ + o)) * N_ + n0 + ln) * T_ + ts * 6;
    *(float2*)&d[0] = make_float2(acc[oo][0], acc[oo][1]);
    *(float2*)&d[2] = make_float2(acc[oo][2], acc[oo][3]);
    *(float2*)&d[4] = make_float2(acc[oo][4], acc[oo][5]);
  }
}

// ---------- stage 3: temporal attention scores ----------
// grid (125, 8), block 256 (240 active): 8 nodes/block staged in LDS
__global__ __launch_bounds__(256) void tatt_s12(
    const float* __restrict__ g, const float* __restrict__ Wp,
    float* __restrict__ s1, float* __restrict__ s2) {
  __shared__ float glds[12288];   // [o 64][nl 8][t 24]
  int b = blockIdx.y, n0 = blockIdx.x * 8;
  int tid = threadIdx.x;
  {
    const float4* src4 = (const float4*)g;
    float4* dst4 = (float4*)glds;
    for (int i = tid; i < 3072; i += 256) {
      int o = i / 48, q = i - o * 48;
      dst4[i] = src4[(size_t)(b * 64 + o) * 6000 + n0 * 6 + q];
    }
  }
  __syncthreads();
  if (tid < 240) {
    int pg = tid / 24, t = tid - pg * 24;
    float a1 = 0.f, a2 = 0.f;
    for (int o = 0; o < 64; ++o) {
      const float* gro = &glds[o * 192 + t];
      const float* wp = &Wp[(size_t)(n0 * 64 + o) * 20 + pg];
      #pragma unroll
      for (int nl = 0; nl < 8; ++nl) {
        float v = gro[nl * 24];
        a1 += v * wp[(size_t)nl * 64 * 20];
        a2 += v * wp[(size_t)nl * 64 * 20 + 10];
      }
    }
    atomicAdd(&s1[(b * T_ + t) * R_ + pg], a1);
    atomicAdd(&s2[(b * T_ + t) * R_ + pg], a2);
  }
}

__global__ __launch_bounds__(64) void tatt_softmax(
    const float* __restrict__ s1, const float* __restrict__ s2, float* __restrict__ Pt) {
  int b = blockIdx.x, t = threadIdx.x;
  if (t >= T_) return;
  float r1[R_];
  #pragma unroll
  for (int r = 0; r < R_; ++r) r1[r] = s1[(b * T_ + t) * R_ + r];
  const float scale = rsqrtf(64000.f);
  float row[T_]; float m = -1e30f;
  for (int j = 0; j < T_; ++j) {
    const float* s2r = s2 + (b * T_ + j) * R_;
    float d = 0.f;
    #pragma unroll
    for (int r = 0; r < R_; ++r) d += r1[r] * s2r[r];
    d *= scale; row[j] = d; m = fmaxf(m, d);
  }
  float s = 0.f;
  for (int j = 0; j < T_; ++j) { float e = __expf(row[j] - m); row[j] = e; s += e; }
  float inv = 1.f / s;
  for (int j = 0; j < T_; ++j) Pt[(b * T_ + t) * T_ + j] = row[j] * inv;
}

__global__ __launch_bounds__(256) void tatt_apply(
    const float* __restrict__ g, const float* __restrict__ Pt, float* __restrict__ x2) {
  __shared__ float P[576];
  int b = blockIdx.y;
  for (int i = threadIdx.x; i < 576; i += 256) P[i] = Pt[b * 576 + i];
  __syncthreads();
  int row = blockIdx.x * 256 + threadIdx.x;
  const float* gp = g + ((size_t)b * 64000 + row) * T_;
  float gr[T_];
  ld24f32(gp, gr);
  float out[T_];
  #pragma unroll
  for (int t = 0; t < T_; ++t) {
    float a = 0.f;
    const float* Pr = &P[t * T_];
    #pragma unroll
    for (int j = 0; j < T_; ++j) a += Pr[j] * gr[j];
    out[t] = a;
  }
  float* xp = x2 + ((size_t)b * 64000 + row) * T_;
  #pragma unroll
  for (int t = 0; t < T_; t += 4)
    *(float4*)&xp[t] = make_float4(out[t], out[t+1], out[t+2], out[t+3]);
}

// ---------- stage 4 (FUSED): conv1+relu -> conv2+relu + 1x1 res + relu -> LN ----------
// 4 nodes/block; thread = (og 16, ln 4, ts 4): 4 o x 6 t
__global__ __launch_bounds__(256) void tail_k(
    const float* __restrict__ x2, const float* __restrict__ x,
    const float* __restrict__ c1w, const float* __restrict__ c1b,
    const float* __restrict__ c2w, const float* __restrict__ c2b,
    const float* __restrict__ rw, const float* __restrict__ rb,
    const float* __restrict__ lg, const float* __restrict__ lb,
    float* __restrict__ outp) {
  __shared__ float xs2[6208];   // conv1 input [c][ln][t] stride 96; later pre-LN [o][97]
  __shared__ float xs [6144];   // residual input [c][ln][t]
  __shared__ float ys [6208];   // conv1 output [o][97] padded
  __shared__ float mu[96], rs[96];
  int b = blockIdx.y, n0 = blockIdx.x * 4;
  int tid = threadIdx.x;
  int og = tid >> 4, ln = (tid >> 2) & 3, ts = tid & 3;
  int ob = og * 4;
  int t0 = ts * 6;
  {
    const float4* s2 = (const float4*)(x2 + ((size_t)b * 64000 + n0) * 24);
    const float4* sx = (const float4*)(x  + ((size_t)b * 64000 + n0) * 24);
    float4* d2 = (float4*)xs2; float4* dx = (float4*)xs;
    for (int i = tid; i < 1536; i += 256) {
      int c = i / 24, j = i - c * 24;
      d2[i] = s2[(size_t)c * 6000 + j];
      dx[i] = sx[(size_t)c * 6000 + j];
    }
  }
  __syncthreads();
  // ---- conv1 ----
  float a1[4][6];
  {
    #pragma unroll
    for (int oo = 0; oo < 4; ++oo) {
      float bz = c1b[ob + oo];
      #pragma unroll
      for (int m = 0; m < 6; ++m) a1[oo][m] = bz;
    }
    const float* base = &xs2[ln * 24];
    for (int c = 0; c < 64; ++c) {
      float vv[8];
      #pragma unroll
      for (int j = 0; j < 8; ++j) {
        int tt = t0 - 2 + j;
        float v = base[c * 96 + (tt < 0 ? 0 : tt)];
        vv[j] = (tt < 0) ? 0.f : v;
      }
      #pragma unroll
      for (int oo = 0; oo < 4; ++oo) {
        float2 w = *(const float2*)&c1w[((size_t)(ob + oo) * 64 + c) * 2];
        #pragma unroll
        for (int m = 0; m < 6; ++m)
          a1[oo][m] += w.y * vv[m + 2] + w.x * vv[m + 1];
      }
    }
    #pragma unroll
    for (int oo = 0; oo < 4; ++oo) {
      float* yr = &ys[(ob + oo) * 97 + ln * 24 + t0];
      #pragma unroll
      for (int m = 0; m < 6; ++m) yr[m] = fmaxf(a1[oo][m], 0.f);
    }
  }
  __syncthreads();
  // ---- conv2 + residual ----
  float pre[4][6];
  {
    float a2[4][6], ar[4][6];
    #pragma unroll
    for (int oo = 0; oo < 4; ++oo) {
      float bz2 = c2b[ob + oo], bzr = rb[ob + oo];
      #pragma unroll
      for (int m = 0; m < 6; ++m) { a2[oo][m] = bz2; ar[oo][m] = bzr; }
    }
    for (int c = 0; c < 64; ++c) {
      float vv[8], xv[6];
      const float* yb = &ys[c * 97 + ln * 24];
      #pragma unroll
      for (int j = 0; j < 8; ++j) {
        int tt = t0 - 2 + j;
        float v = yb[tt < 0 ? 0 : tt];
        vv[j] = (tt < 0) ? 0.f : v;
      }
      const float* xb = &xs[c * 96 + ln * 24 + t0];
      #pragma unroll
      for (int m = 0; m < 6; ++m) xv[m] = xb[m];
      #pragma unroll
      for (int oo = 0; oo < 4; ++oo) {
        float2 w = *(const float2*)&c2w[((size_t)(ob + oo) * 64 + c) * 2];
        float wr = rw[(size_t)(ob + oo) * 64 + c];
        #pragma unroll
        for (int m = 0; m < 6; ++m) {
          a2[oo][m] += w.y * vv[m + 2] + w.x * vv[m];
          ar[oo][m] += wr * xv[m];
        }
      }
    }
    #pragma unroll
    for (int oo = 0; oo < 4; ++oo)
      #pragma unroll
      for (int m = 0; m < 6; ++m)
        pre[oo][m] = fmaxf(fmaxf(a2[oo][m], 0.f) + ar[oo][m], 0.f);
  }
  __syncthreads();   // done with xs2 conv input; reuse as padded pre-LN tile
  #pragma unroll
  for (int oo = 0; oo < 4; ++oo) {
    float* pr = &xs2[(ob + oo) * 97 + ln * 24 + t0];
    #pragma unroll
    for (int m = 0; m < 6; ++m) pr[m] = pre[oo][m];
  }
  __syncthreads();
  if (tid < 96) {
    float s = 0.f, q = 0.f;
    for (int c = 0; c < 64; ++c) {
      float v = xs2[c * 97 + tid];
      s += v; q += v * v;
    }
    float m = s * (1.f / 64.f);
    float var = q * (1.f / 64.f) - m * m;
    mu[tid] = m;
    rs[tid] = rsqrtf(var + 1e-5f);
  }
  __syncthreads();
  #pragma unroll
  for (int oo = 0; oo < 4; ++oo) {
    int o = ob + oo;
    float go = lg[o], bo = lb[o];
    float* d = outp + (((size_t)(b * 64 + o)) * 1000 + n0 + ln) * 24 + t0;
    float w[6];
    #pragma unroll
    for (int m = 0; m < 6; ++m)
      w[m] = (pre[oo][m] - mu[ln * 24 + t0 + m]) * rs[ln * 24 + t0 + m] * go + bo;
    *(float2*)&d[0] = make_float2(w[0], w[1]);
    *(float2*)&d[2] = make_float2(w[2], w[3]);
    *(float2*)&d[4] = make_float2(w[4], w[5]);
  }
}

extern "C" void kernel_launch(void* const* d_in, const int* in_sizes, int n_in,
                              void* d_out, int out_size, void* d_ws, size_t ws_size,
                              hipStream_t stream) {
  const float* x     = (const float*)d_in[0];
  const float* Aadj  = (const float*)d_in[1];
  const float* a0W1  = (const float*)d_in[2];
  const float* a0W2  = (const float*)d_in[3];
  const float* gW1   = (const float*)d_in[4];
  const float* gW2   = (const float*)d_in[5];
  const float* gcnW  = (const float*)d_in[6];
  const float* tW1   = (const float*)d_in[7];
  const float* tW2   = (const float*)d_in[8];
  const float* c1w   = (const float*)d_in[9];
  const float* c1b   = (const float*)d_in[10];
  const float* c2w   = (const float*)d_in[11];
  const float* c2b   = (const float*)d_in[12];
  const float* rw    = (const float*)d_in[13];
  const float* rb    = (const float*)d_in[14];
  const float* lng   = (const float*)d_in[15];
  const float* lnb   = (const float*)d_in[16];
  float* out = (float*)d_out;

  float* ws = (float*)d_ws;
  float* R1   = ws;                    // 12,288,000: x1tr -> x2
  float* U    = R1 + 12288000;         // 12,288,000: Xbt+Agb (bf16), later g (f32)
  float* D    = U + 12288000;          // 12,288,000: g1
  float* s1_0 = D + 12288000;          // 5120
  float* s2_0 = s1_0 + 5120;           // 5120
  float* P0   = s2_0 + 5120;           // 32768
  float* s1g  = P0 + 32768;            // 80000
  float* s2gT = s1g + 80000;           // 80000
  float* s1t  = s2gT + 80000;          // 1920
  float* s2t  = s1t + 1920;            // 1920
  float* Ptb  = s2t + 1920;            // 4608
  float* Wp0  = Ptb + 4608;            // 480000
  float* Wgp  = Wp0 + 480000;          // 30720
  float* Wtp  = Wgp + 30720;           // 1280000
  ushortt* Xbt = (ushortt*)U;
  ushortt* Agb = (ushortt*)(U + 6291456);
  float* g = U;
  if (ws_size < (size_t)38866176 * 4) return;

  // weight packing
  pack_w<<<1875, 256, 0, stream>>>(a0W1, a0W2, Wp0, 24000);
  pack_w<<<120, 256, 0, stream>>>(gW1, gW2, Wgp, 1536);
  pack_w<<<5000, 256, 0, stream>>>(tW1, tW2, Wtp, 64000);
  // stage 1: channel attention
  att0_s12<<<256, 256, 0, stream>>>(x, Wp0, s1_0, s2_0);
  att0_softmax<<<8, 64, 0, stream>>>(s1_0, s2_0, P0);
  att0_apply<<<dim3(250, 8), 256, 0, stream>>>(x, P0, R1);
  // stage 2: gated GCN
  gatt_s12<<<2000, 256, 0, stream>>>(R1, Wgp, s1g, s2gT);
  transpose_x1<<<dim3(24, 16, 8), 256, 0, stream>>>(R1, Xbt);
  gatt_scores<<<8000, 256, 0, stream>>>(s1g, s2gT, Aadj, Agb);
  gemm_mfma<<<dim3(12, 8, 8), 256, 0, stream>>>(Agb, Xbt, D);
  gcn_out<<<dim3(250, 8), 256, 0, stream>>>(D, gcnW, g);
  // stage 3: temporal attention
  zerok<<<15, 256, 0, stream>>>(s1t, 3840);
  tatt_s12<<<dim3(125, 8), 256, 0, stream>>>(g, Wtp, s1t, s2t);
  tatt_softmax<<<8, 32, 0, stream>>>(s1t, s2t, Ptb);
  tatt_apply<<<dim3(250, 8), 256, 0, stream>>>(g, Ptb, R1);
  // stage 4: fused TCN tail + residual + LN
  tail_k<<<dim3(250, 8), 256, 0, stream>>>(R1, x, c1w, c1b, c2w, c2b,
                                           rw, rb, lng, lnb, out);
}

// Round 6
// 623.801 us; speedup vs baseline: 4.2696x; 1.1489x over previous
//
#include <hip/hip_runtime.h>
#include <hip/hip_bf16.h>

typedef unsigned int u32;
typedef unsigned short ushortt;

#define B_  8
#define C_  64
#define N_  1000
#define T_  24
#define R_  10
#define NT_ 24000   // N*T
#define CT_ 1536    // C*T
#define NC_ 64000   // N*Co

typedef __attribute__((ext_vector_type(8))) short bf8v;
typedef __attribute__((ext_vector_type(4))) float f4v;

__device__ __forceinline__ ushortt f2b_bits(float f) {
  u32 x = __float_as_uint(f);
  u32 r = (x + 0x7fffu + ((x >> 16) & 1u)) >> 16;   // round-to-nearest-even
  return (ushortt)r;
}

__device__ __forceinline__ float blockSum256(float v, float* red) {
  red[threadIdx.x] = v; __syncthreads();
  #pragma unroll
  for (int s = 128; s > 0; s >>= 1) {
    if (threadIdx.x < s) red[threadIdx.x] += red[threadIdx.x + s];
    __syncthreads();
  }
  float r = red[0]; __syncthreads();
  return r;
}
__device__ __forceinline__ float blockMax256(float v, float* red) {
  red[threadIdx.x] = v; __syncthreads();
  #pragma unroll
  for (int s = 128; s > 0; s >>= 1) {
    if (threadIdx.x < s) red[threadIdx.x] = fmaxf(red[threadIdx.x], red[threadIdx.x + s]);
    __syncthreads();
  }
  float r = red[0]; __syncthreads();
  return r;
}

__device__ __forceinline__ void ld24f32(const float* p, float* v) {
  #pragma unroll
  for (int t = 0; t < 24; t += 4) {
    float4 f = *(const float4*)&p[t];
    v[t] = f.x; v[t+1] = f.y; v[t+2] = f.z; v[t+3] = f.w;
  }
}

// ---------- utility ----------
__global__ __launch_bounds__(256) void zerok(float* p, int n) {
  int i = blockIdx.x * 256 + threadIdx.x;
  if (i < n) p[i] = 0.f;
}

// pack W1[K][10] and W2[10][K] -> Wp[K][20]
__global__ __launch_bounds__(256) void pack_w(
    const float* __restrict__ W1, const float* __restrict__ W2,
    float* __restrict__ Wp, int K) {
  int i = blockIdx.x * 256 + threadIdx.x;
  if (i >= K * 20) return;
  int k = i / 20, r = i - k * 20;
  Wp[i] = (r < 10) ? W1[(size_t)k * 10 + r] : W2[(size_t)(r - 10) * K + k];
}

// pack tail weights to bf16 A-matrices:
// [0:8192)  Wc1b[2][64][64]  tap0 = c1w[...,1] (current), tap1 = c1w[...,0] (t-1)
// [8192:16384) Wc2b[2][64][64]
// [16384:20480) Wrb[64][64]
__global__ __launch_bounds__(256) void pack_tailw(
    const float* __restrict__ c1w, const float* __restrict__ c2w,
    const float* __restrict__ rw, ushortt* __restrict__ Wt) {
  int i = blockIdx.x * 256 + threadIdx.x;
  if (i >= 20480) return;
  float v;
  if (i < 8192) {
    int tap = i >> 12, o = (i >> 6) & 63, c = i & 63;
    v = c1w[(size_t)(o * 64 + c) * 2 + (tap ? 0 : 1)];
  } else if (i < 16384) {
    int j = i - 8192;
    int tap = j >> 12, o = (j >> 6) & 63, c = j & 63;
    v = c2w[(size_t)(o * 64 + c) * 2 + (tap ? 0 : 1)];
  } else {
    int j = i - 16384;
    v = rw[j];
  }
  Wt[i] = f2b_bits(v);
}

// ---------- stage 1: channel attention scores ----------
__global__ __launch_bounds__(256) void att0_s12(
    const float* __restrict__ x, const float* __restrict__ Wp,
    float* __restrict__ s1, float* __restrict__ s2) {
  __shared__ float red[5120];
  int rid = threadIdx.x >> 7, ks = threadIdx.x & 127;
  int row = blockIdx.x * 2 + rid;
  const float* xr = x + (size_t)row * NT_;
  float a[20];
  #pragma unroll
  for (int r = 0; r < 20; ++r) a[r] = 0.f;
  for (int k = ks; k < NT_; k += 128) {
    float xv = xr[k];
    const float4* wp4 = (const float4*)&Wp[(size_t)k * 20];
    float4 wa = wp4[0], wb = wp4[1], wc = wp4[2], wd = wp4[3], we = wp4[4];
    float wv[20] = {wa.x,wa.y,wa.z,wa.w, wb.x,wb.y,wb.z,wb.w, wc.x,wc.y,wc.z,wc.w,
                    wd.x,wd.y,wd.z,wd.w, we.x,we.y,we.z,we.w};
    #pragma unroll
    for (int r = 0; r < 20; ++r) a[r] += xv * wv[r];
  }
  #pragma unroll
  for (int r = 0; r < 20; ++r) red[threadIdx.x * 20 + r] = a[r];
  __syncthreads();
  if (threadIdx.x < 40) {
    int rid2 = threadIdx.x / 20, r = threadIdx.x % 20;
    float s = 0.f;
    for (int l = 0; l < 128; ++l) s += red[(rid2 * 128 + l) * 20 + r];
    int orow = blockIdx.x * 2 + rid2;
    if (r < 10) s1[orow * 10 + r] = s;
    else        s2[orow * 10 + (r - 10)] = s;
  }
}

__global__ __launch_bounds__(64) void att0_softmax(
    const float* __restrict__ s1, const float* __restrict__ s2, float* __restrict__ P) {
  int b = blockIdx.x, i = threadIdx.x;
  float r1[R_];
  #pragma unroll
  for (int r = 0; r < R_; ++r) r1[r] = s1[(b * 64 + i) * R_ + r];
  const float scale = rsqrtf(24000.f);
  float row[64]; float m = -1e30f;
  for (int j = 0; j < 64; ++j) {
    const float* s2r = s2 + (size_t)(b * 64 + j) * R_;
    float d = 0.f;
    #pragma unroll
    for (int r = 0; r < R_; ++r) d += r1[r] * s2r[r];
    d *= scale; row[j] = d; m = fmaxf(m, d);
  }
  float s = 0.f;
  for (int j = 0; j < 64; ++j) { float e = __expf(row[j] - m); row[j] = e; s += e; }
  float inv = 1.f / s;
  for (int j = 0; j < 64; ++j) P[((size_t)b * 64 + i) * 64 + j] = row[j] * inv;
}

__global__ __launch_bounds__(256) void att0_apply(
    const float* __restrict__ x, const float* __restrict__ P, float* __restrict__ x1tr) {
  __shared__ float Pss[4160];
  __shared__ float xt[6144];
  int b = blockIdx.y, n0 = blockIdx.x * 4;
  int tid = threadIdx.x;
  for (int i = tid; i < 4096; i += 256)
    Pss[(i >> 6) * 65 + (i & 63)] = P[(size_t)b * 4096 + i];
  {
    const float4* src4 = (const float4*)x;
    float4* dst4 = (float4*)xt;
    for (int i = tid; i < 1536; i += 256) {
      int j = i / 24, q = i - j * 24;
      dst4[i] = src4[(size_t)(b * 64 + j) * 6000 + n0 * 6 + q];
    }
  }
  __syncthreads();
  int ig = tid >> 4, ln = (tid >> 2) & 3, ts = tid & 3;
  float acc[4][6];
  #pragma unroll
  for (int ii = 0; ii < 4; ++ii)
    #pragma unroll
    for (int m = 0; m < 6; ++m) acc[ii][m] = 0.f;
  const float* base = &xt[ln * 24 + ts * 6];
  #pragma unroll 4
  for (int j = 0; j < 64; ++j) {
    float vj[6];
    #pragma unroll
    for (int m = 0; m < 6; ++m) vj[m] = base[j * 96 + m];
    #pragma unroll
    for (int ii = 0; ii < 4; ++ii) {
      float p = Pss[(ig * 4 + ii) * 65 + j];
      #pragma unroll
      for (int m = 0; m < 6; ++m) acc[ii][m] += p * vj[m];
    }
  }
  float* drow = x1tr + ((size_t)b * N_ + n0 + ln) * CT_ + ts * 6;
  #pragma unroll
  for (int ii = 0; ii < 4; ++ii) {
    float* d = drow + (ig * 4 + ii) * 24;
    *(float2*)&d[0] = make_float2(acc[ii][0], acc[ii][1]);
    *(float2*)&d[2] = make_float2(acc[ii][2], acc[ii][3]);
    *(float2*)&d[4] = make_float2(acc[ii][4], acc[ii][5]);
  }
}

// ---------- transpose x1tr -> Xbt bf16 ----------
__global__ __launch_bounds__(256) void transpose_x1(
    const float* __restrict__ x1tr, ushortt* __restrict__ Xbt) {
  __shared__ float s[64][65];
  int b = blockIdx.z, n0 = blockIdx.y * 64, c0 = blockIdx.x * 64;
  int tid = threadIdx.x;
  int r = tid >> 2, cc = (tid & 3) * 16;
  if (n0 + r < N_) {
    const float* src = x1tr + ((size_t)b * N_ + n0 + r) * CT_ + c0 + cc;
    #pragma unroll
    for (int i = 0; i < 16; i += 4) {
      float4 v = *(const float4*)&src[i];
      s[r][cc + i] = v.x; s[r][cc + i + 1] = v.y;
      s[r][cc + i + 2] = v.z; s[r][cc + i + 3] = v.w;
    }
  } else {
    #pragma unroll
    for (int i = 0; i < 16; ++i) s[r][cc + i] = 0.f;
  }
  __syncthreads();
  ushortt* dst = Xbt + ((size_t)b * CT_ + c0 + r) * 1024 + n0 + cc;
  #pragma unroll
  for (int i = 0; i < 16; ++i) dst[i] = f2b_bits(s[cc + i][r]);
}

// ---------- stage 2: gate scores ----------
__global__ __launch_bounds__(256) void gatt_s12(
    const float* __restrict__ xg, const float* __restrict__ Wp,
    float* __restrict__ s1, float* __restrict__ s2T) {
  __shared__ float xs[6144];
  __shared__ float red[5120];
  int bn0 = blockIdx.x * 4;
  int tid = threadIdx.x;
  {
    const float4* src4 = (const float4*)(xg + (size_t)bn0 * CT_);
    float4* dst4 = (float4*)xs;
    for (int i = tid; i < 1536; i += 256) dst4[i] = src4[i];
  }
  __syncthreads();
  int rid = tid >> 6, ks = tid & 63;
  float a[20];
  #pragma unroll
  for (int r = 0; r < 20; ++r) a[r] = 0.f;
  for (int k = ks; k < CT_; k += 64) {
    float xv = xs[rid * CT_ + k];
    const float4* wp4 = (const float4*)&Wp[(size_t)k * 20];
    float4 wa = wp4[0], wb = wp4[1], wc = wp4[2], wd = wp4[3], we = wp4[4];
    float wv[20] = {wa.x,wa.y,wa.z,wa.w, wb.x,wb.y,wb.z,wb.w, wc.x,wc.y,wc.z,wc.w,
                    wd.x,wd.y,wd.z,wd.w, we.x,we.y,we.z,we.w};
    #pragma unroll
    for (int r = 0; r < 20; ++r) a[r] += xv * wv[r];
  }
  #pragma unroll
  for (int r = 0; r < 20; ++r) red[tid * 20 + r] = a[r];
  __syncthreads();
  if (tid < 80) {
    int rid2 = tid / 20, r = tid % 20;
    float s = 0.f;
    for (int l = 0; l < 64; ++l) s += red[(rid2 * 64 + l) * 20 + r];
    int row = bn0 + rid2;
    int b = row / N_, n = row - b * N_;
    if (r < 10) s1[row * 10 + r] = s;
    else        s2T[((size_t)b * 10 + (r - 10)) * N_ + n] = s;
  }
}

__global__ __launch_bounds__(256) void gatt_scores(
    const float* __restrict__ s1, const float* __restrict__ s2T,
    const float* __restrict__ Aadj, ushortt* __restrict__ Agb) {
  __shared__ float p[N_];
  __shared__ float r1[R_];
  __shared__ float red[256];
  int b = blockIdx.x / N_, n = blockIdx.x % N_;
  if (threadIdx.x < R_) r1[threadIdx.x] = s1[((size_t)b * N_ + n) * R_ + threadIdx.x];
  __syncthreads();
  const float scale = rsqrtf(1536.f);
  const float* s2b = s2T + (size_t)b * 10 * N_;
  float lmax = -1e30f;
  for (int m = threadIdx.x; m < N_; m += 256) {
    float d = 0.f;
    #pragma unroll
    for (int r = 0; r < R_; ++r) d += r1[r] * s2b[r * N_ + m];
    d *= scale; p[m] = d; lmax = fmaxf(lmax, d);
  }
  float gmax = blockMax256(lmax, red);
  float lsum = 0.f;
  for (int m = threadIdx.x; m < N_; m += 256) {
    float e = __expf(p[m] - gmax); p[m] = e; lsum += e;
  }
  float gsum = blockSum256(lsum, red);
  float inv = 1.f / gsum;
  ushortt* agr = Agb + ((size_t)b * 1024 + n) * 1024;
  const float* ar = Aadj + (size_t)n * N_;
  for (int m = threadIdx.x; m < 1024; m += 256) {
    float v = (m < N_) ? p[m] * inv * ar[m] : 0.f;
    agr[m] = f2b_bits(v);
  }
}

// ---------- batched MFMA GEMM ----------
__global__ __launch_bounds__(256) void gemm_mfma(
    const ushortt* __restrict__ Agb, const ushortt* __restrict__ Xbt,
    float* __restrict__ g1) {
  __shared__ ushortt As[4096];
  __shared__ ushortt Bs[4096];
  const int b = blockIdx.z;
  const int n0 = blockIdx.x * 128;
  const int m0 = blockIdx.y * 128;
  const ushortt* Ab = Agb + (size_t)b * 1024 * 1024;
  const ushortt* Bb = Xbt + (size_t)b * 1536 * 1024;
  const int tid = threadIdx.x;
  const int wave = tid >> 6, lane = tid & 63;
  const int wr = (wave >> 1) * 64, wc = (wave & 1) * 64;
  const int lrow = lane >> 2;
  const int lcol = (lane & 3) * 8;
  const int q = lane >> 4, l15 = lane & 15;

  f4v acc[4][4];
  #pragma unroll
  for (int i = 0; i < 4; ++i)
    #pragma unroll
    for (int j = 0; j < 4; ++j) acc[i][j] = (f4v){0.f, 0.f, 0.f, 0.f};

  const ushortt* gA = Ab + (size_t)(m0 + wave * 16 + lrow) * 1024 + lcol;
  const ushortt* gB = Bb + (size_t)(n0 + wave * 16 + lrow) * 1024 + lcol;
  ushortt* lA = &As[wave * 16 * 32];
  ushortt* lB = &Bs[wave * 16 * 32];

  for (int k0 = 0; k0 < 1024; k0 += 32) {
    __syncthreads();
    __builtin_amdgcn_global_load_lds(
      (const __attribute__((address_space(1))) void*)(gA + k0),
      (__attribute__((address_space(3))) void*)lA, 16, 0, 0);
    __builtin_amdgcn_global_load_lds(
      (const __attribute__((address_space(1))) void*)(gA + (size_t)64 * 1024 + k0),
      (__attribute__((address_space(3))) void*)(lA + 64 * 32), 16, 0, 0);
    __builtin_amdgcn_global_load_lds(
      (const __attribute__((address_space(1))) void*)(gB + k0),
      (__attribute__((address_space(3))) void*)lB, 16, 0, 0);
    __builtin_amdgcn_global_load_lds(
      (const __attribute__((address_space(1))) void*)(gB + (size_t)64 * 1024 + k0),
      (__attribute__((address_space(3))) void*)(lB + 64 * 32), 16, 0, 0);
    __syncthreads();
    bf8v af[4], bfr[4];
    #pragma unroll
    for (int i = 0; i < 4; ++i)
      af[i] = *(const bf8v*)&As[(wr + i * 16 + l15) * 32 + q * 8];
    #pragma unroll
    for (int j = 0; j < 4; ++j)
      bfr[j] = *(const bf8v*)&Bs[(wc + j * 16 + l15) * 32 + q * 8];
    #pragma unroll
    for (int i = 0; i < 4; ++i)
      #pragma unroll
      for (int j = 0; j < 4; ++j)
        acc[i][j] = __builtin_amdgcn_mfma_f32_16x16x32_bf16(af[i], bfr[j], acc[i][j], 0, 0, 0);
  }
  #pragma unroll
  for (int i = 0; i < 4; ++i) {
    int rbase = m0 + wr + i * 16 + q * 4;
    #pragma unroll
    for (int r = 0; r < 4; ++r) {
      int gm = rbase + r;
      if (gm < N_) {
        float* dst = g1 + ((size_t)b * N_ + gm) * CT_ + n0 + wc + l15;
        #pragma unroll
        for (int j = 0; j < 4; ++j) dst[j * 16] = acc[i][j][r];
      }
    }
  }
}

// ---------- gcn_out ----------
__global__ __launch_bounds__(256) void gcn_out(
    const float* __restrict__ g1, const float* __restrict__ W, float* __restrict__ g) {
  __shared__ float gs[6160];
  __shared__ float Ws[4096];
  int b = blockIdx.y, n0 = blockIdx.x * 4;
  int tid = threadIdx.x;
  {
    const float4* src4 = (const float4*)g1;
    float4* dst4 = (float4*)gs;
    for (int i = tid; i < 1536; i += 256) {
      int ln = i / 384, q = i - ln * 384;
      dst4[ln * 385 + q] = src4[(size_t)(b * N_ + n0 + ln) * 384 + q];
    }
  }
  for (int i = tid; i < 4096; i += 256) Ws[i] = W[i];
  __syncthreads();
  int og = tid >> 4, ln = (tid >> 2) & 3, ts = tid & 3;
  float acc[4][6];
  #pragma unroll
  for (int oo = 0; oo < 4; ++oo)
    #pragma unroll
    for (int m = 0; m < 6; ++m) acc[oo][m] = 0.f;
  const float* base = &gs[ln * 1540 + ts * 6];
  #pragma unroll 4
  for (int c = 0; c < 64; ++c) {
    float v[6];
    #pragma unroll
    for (int m = 0; m < 6; ++m) v[m] = base[c * 24 + m];
    float4 w4 = *(const float4*)&Ws[c * 64 + og * 4];
    float wv[4] = {w4.x, w4.y, w4.z, w4.w};
    #pragma unroll
    for (int oo = 0; oo < 4; ++oo)
      #pragma unroll
      for (int m = 0; m < 6; ++m) acc[oo][m] += wv[oo] * v[m];
  }
  #pragma unroll
  for (int oo = 0; oo < 4; ++oo) {
    int o = og * 4 + oo;
    float* d = g + (((size_t)(b * C_ + o)) * N_ + n0 + ln) * T_ + ts * 6;
    *(float2*)&d[0] = make_float2(acc[oo][0], acc[oo][1]);
    *(float2*)&d[2] = make_float2(acc[oo][2], acc[oo][3]);
    *(float2*)&d[4] = make_float2(acc[oo][4], acc[oo][5]);
  }
}

// ---------- stage 3: temporal attention ----------
__global__ __launch_bounds__(256) void tatt_s12(
    const float* __restrict__ g, const float* __restrict__ Wp,
    float* __restrict__ s1, float* __restrict__ s2) {
  __shared__ float glds[12288];
  int b = blockIdx.y, n0 = blockIdx.x * 8;
  int tid = threadIdx.x;
  {
    const float4* src4 = (const float4*)g;
    float4* dst4 = (float4*)glds;
    for (int i = tid; i < 3072; i += 256) {
      int o = i / 48, q = i - o * 48;
      dst4[i] = src4[(size_t)(b * 64 + o) * 6000 + n0 * 6 + q];
    }
  }
  __syncthreads();
  if (tid < 240) {
    int pg = tid / 24, t = tid - pg * 24;
    float a1 = 0.f, a2 = 0.f;
    for (int o = 0; o < 64; ++o) {
      const float* gro = &glds[o * 192 + t];
      const float* wp = &Wp[(size_t)(n0 * 64 + o) * 20 + pg];
      #pragma unroll
      for (int nl = 0; nl < 8; ++nl) {
        float v = gro[nl * 24];
        a1 += v * wp[(size_t)nl * 64 * 20];
        a2 += v * wp[(size_t)nl * 64 * 20 + 10];
      }
    }
    atomicAdd(&s1[(b * T_ + t) * R_ + pg], a1);
    atomicAdd(&s2[(b * T_ + t) * R_ + pg], a2);
  }
}

__global__ __launch_bounds__(64) void tatt_softmax(
    const float* __restrict__ s1, const float* __restrict__ s2, float* __restrict__ Pt) {
  int b = blockIdx.x, t = threadIdx.x;
  if (t >= T_) return;
  float r1[R_];
  #pragma unroll
  for (int r = 0; r < R_; ++r) r1[r] = s1[(b * T_ + t) * R_ + r];
  const float scale = rsqrtf(64000.f);
  float row[T_]; float m = -1e30f;
  for (int j = 0; j < T_; ++j) {
    const float* s2r = s2 + (b * T_ + j) * R_;
    float d = 0.f;
    #pragma unroll
    for (int r = 0; r < R_; ++r) d += r1[r] * s2r[r];
    d *= scale; row[j] = d; m = fmaxf(m, d);
  }
  float s = 0.f;
  for (int j = 0; j < T_; ++j) { float e = __expf(row[j] - m); row[j] = e; s += e; }
  float inv = 1.f / s;
  for (int j = 0; j < T_; ++j) Pt[(b * T_ + t) * T_ + j] = row[j] * inv;
}

__global__ __launch_bounds__(256) void tatt_apply(
    const float* __restrict__ g, const float* __restrict__ Pt, float* __restrict__ x2) {
  __shared__ float P[576];
  int b = blockIdx.y;
  for (int i = threadIdx.x; i < 576; i += 256) P[i] = Pt[b * 576 + i];
  __syncthreads();
  int row = blockIdx.x * 256 + threadIdx.x;
  const float* gp = g + ((size_t)b * 64000 + row) * T_;
  float gr[T_];
  ld24f32(gp, gr);
  float out[T_];
  #pragma unroll
  for (int t = 0; t < T_; ++t) {
    float a = 0.f;
    const float* Pr = &P[t * T_];
    #pragma unroll
    for (int j = 0; j < T_; ++j) a += Pr[j] * gr[j];
    out[t] = a;
  }
  float* xp = x2 + ((size_t)b * 64000 + row) * T_;
  #pragma unroll
  for (int t = 0; t < T_; t += 4)
    *(float4*)&xp[t] = make_float4(out[t], out[t+1], out[t+2], out[t+3]);
}

// ---------- stage 4 (MFMA tail): conv1 -> conv2 + res -> LN ----------
// grid (250, 8), 256 threads = 4 waves; wave w owns node nl=w (cols 32w..32w+31).
// Column layout per node: s=0,1 zero guards; s=2..25 <-> t=0..23; s=26..31 zero pad.
// Tiles in LDS: [kblock 8][col 128][8 ushorts] (16B-aligned b128 fragments).
#define CSB 1024
__global__ __launch_bounds__(256, 3) void tail_k(
    const float* __restrict__ x2, const float* __restrict__ x,
    const ushortt* __restrict__ Wt,
    const float* __restrict__ c1b, const float* __restrict__ c2b,
    const float* __restrict__ rb,
    const float* __restrict__ lg, const float* __restrict__ lb,
    float* __restrict__ outp) {
  __shared__ ushortt X2c[8192];
  __shared__ ushortt Y1c[8192];
  __shared__ ushortt Xrc[8192];
  __shared__ float mu[96], rs[96];
  ushortt* preS = X2c;   // overlay: X2c dead after conv1
  int b = blockIdx.y, n0 = blockIdx.x * 4;
  int tid = threadIdx.x;
  int wave = tid >> 6, lane = tid & 63;
  int q = lane >> 4, l15 = lane & 15;

  // stage x2 / x tiles
  for (int i = tid; i < 6144; i += 256) {
    int c = i / 96, rem = i - c * 96;
    int nl = rem / 24, t = rem - nl * 24;
    int col = nl * 32 + 2 + t;
    size_t gidx = ((size_t)(b * 64 + c) * 1000 + n0 + nl) * 24 + t;
    int li = (c >> 3) * CSB + col * 8 + (c & 7);
    X2c[li] = f2b_bits(x2[gidx]);
    Xrc[li] = f2b_bits(x[gidx]);
  }
  { // zero guard/pad cols: 8 kblk x 32 cols, one 16B chunk per thread
    int blk = tid >> 5, gi = tid & 31;
    int nl = gi >> 3, gs = gi & 7;
    int s = (gs < 2) ? gs : (24 + gs);
    int col = nl * 32 + s;
    uint4 z = make_uint4(0, 0, 0, 0);
    *(uint4*)&X2c[blk * CSB + col * 8] = z;
    *(uint4*)&Xrc[blk * CSB + col * 8] = z;
  }
  __syncthreads();

  // ---- conv1: D[o][col] = W1@X2 + W0@X2(col-1) ----
  f4v acc1[2][4];
  #pragma unroll
  for (int ct = 0; ct < 2; ++ct)
    #pragma unroll
    for (int mt = 0; mt < 4; ++mt) acc1[ct][mt] = (f4v){0.f, 0.f, 0.f, 0.f};
  #pragma unroll
  for (int ki = 0; ki < 2; ++ki) {
    bf8v a0[4], a1[4];
    #pragma unroll
    for (int mt = 0; mt < 4; ++mt) {
      a0[mt] = *(const bf8v*)&Wt[(mt * 16 + l15) * 64 + ki * 32 + q * 8];
      a1[mt] = *(const bf8v*)&Wt[4096 + (mt * 16 + l15) * 64 + ki * 32 + q * 8];
    }
    #pragma unroll
    for (int ct = 0; ct < 2; ++ct) {
      int col = wave * 32 + ct * 16 + l15;
      int colp = (col == 0) ? 0 : col - 1;
      bf8v bc = *(const bf8v*)&X2c[(ki * 4 + q) * CSB + col * 8];
      bf8v bp = *(const bf8v*)&X2c[(ki * 4 + q) * CSB + colp * 8];
      #pragma unroll
      for (int mt = 0; mt < 4; ++mt) {
        acc1[ct][mt] = __builtin_amdgcn_mfma_f32_16x16x32_bf16(a0[mt], bc, acc1[ct][mt], 0, 0, 0);
        acc1[ct][mt] = __builtin_amdgcn_mfma_f32_16x16x32_bf16(a1[mt], bp, acc1[ct][mt], 0, 0, 0);
      }
    }
  }
  // epilogue 1: bias + relu -> Y1c (zeros in guard/pad cols)
  #pragma unroll
  for (int ct = 0; ct < 2; ++ct) {
    int s = ct * 16 + l15;
    int col = wave * 32 + s;
    bool v = (s >= 2 && s <= 25);
    #pragma unroll
    for (int mt = 0; mt < 4; ++mt) {
      int o0 = mt * 16 + q * 4;
      float4 bb = *(const float4*)&c1b[o0];
      float y0 = v ? fmaxf(acc1[ct][mt][0] + bb.x, 0.f) : 0.f;
      float y1 = v ? fmaxf(acc1[ct][mt][1] + bb.y, 0.f) : 0.f;
      float y2 = v ? fmaxf(acc1[ct][mt][2] + bb.z, 0.f) : 0.f;
      float y3 = v ? fmaxf(acc1[ct][mt][3] + bb.w, 0.f) : 0.f;
      u32 lo = (u32)f2b_bits(y0) | ((u32)f2b_bits(y1) << 16);
      u32 hi = (u32)f2b_bits(y2) | ((u32)f2b_bits(y3) << 16);
      *(uint2*)&Y1c[(o0 >> 3) * CSB + col * 8 + (o0 & 7)] = make_uint2(lo, hi);
    }
  }
  __syncthreads();

  // ---- conv2 (taps col, col-2 from Y1c) + residual (Xrc) ----
  f4v accA[2][4], accR[2][4];
  #pragma unroll
  for (int ct = 0; ct < 2; ++ct)
    #pragma unroll
    for (int mt = 0; mt < 4; ++mt) {
      accA[ct][mt] = (f4v){0.f, 0.f, 0.f, 0.f};
      accR[ct][mt] = (f4v){0.f, 0.f, 0.f, 0.f};
    }
  #pragma unroll
  for (int ki = 0; ki < 2; ++ki) {
    bf8v c0[4], c1t[4], rrf[4];
    #pragma unroll
    for (int mt = 0; mt < 4; ++mt) {
      c0[mt]  = *(const bf8v*)&Wt[8192 + (mt * 16 + l15) * 64 + ki * 32 + q * 8];
      c1t[mt] = *(const bf8v*)&Wt[12288 + (mt * 16 + l15) * 64 + ki * 32 + q * 8];
      rrf[mt] = *(const bf8v*)&Wt[16384 + (mt * 16 + l15) * 64 + ki * 32 + q * 8];
    }
    #pragma unroll
    for (int ct = 0; ct < 2; ++ct) {
      int col = wave * 32 + ct * 16 + l15;
      int colp2 = (col < 2) ? col : col - 2;
      bf8v bc = *(const bf8v*)&Y1c[(ki * 4 + q) * CSB + col * 8];
      bf8v bp = *(const bf8v*)&Y1c[(ki * 4 + q) * CSB + colp2 * 8];
      bf8v bx = *(const bf8v*)&Xrc[(ki * 4 + q) * CSB + col * 8];
      #pragma unroll
      for (int mt = 0; mt < 4; ++mt) {
        accA[ct][mt] = __builtin_amdgcn_mfma_f32_16x16x32_bf16(c0[mt], bc, accA[ct][mt], 0, 0, 0);
        accA[ct][mt] = __builtin_amdgcn_mfma_f32_16x16x32_bf16(c1t[mt], bp, accA[ct][mt], 0, 0, 0);
        accR[ct][mt] = __builtin_amdgcn_mfma_f32_16x16x32_bf16(rrf[mt], bx, accR[ct][mt], 0, 0, 0);
      }
    }
  }
  // epilogue 2: relu(conv2+b2) + (res+rb), relu -> pre (regs) + preS (bf16 LDS)
  float pre[2][4][4];
  #pragma unroll
  for (int ct = 0; ct < 2; ++ct) {
    int s = ct * 16 + l15;
    bool v = (s >= 2 && s <= 25);
    int p = wave * 24 + s - 2;
    #pragma unroll
    for (int mt = 0; mt < 4; ++mt) {
      int o0 = mt * 16 + q * 4;
      float4 b2 = *(const float4*)&c2b[o0];
      float4 rbv = *(const float4*)&rb[o0];
      float bb2[4] = {b2.x, b2.y, b2.z, b2.w};
      float brv[4] = {rbv.x, rbv.y, rbv.z, rbv.w};
      #pragma unroll
      for (int r = 0; r < 4; ++r) {
        float a = fmaxf(accA[ct][mt][r] + bb2[r], 0.f) + accR[ct][mt][r] + brv[r];
        pre[ct][mt][r] = fmaxf(a, 0.f);
      }
      if (v) {
        u32 lo = (u32)f2b_bits(pre[ct][mt][0]) | ((u32)f2b_bits(pre[ct][mt][1]) << 16);
        u32 hi = (u32)f2b_bits(pre[ct][mt][2]) | ((u32)f2b_bits(pre[ct][mt][3]) << 16);
        *(uint2*)&preS[p * 68 + o0] = make_uint2(lo, hi);
      }
    }
  }
  __syncthreads();
  // LN stats over o for each of 96 (node,t) pairs
  if (tid < 96) {
    const ushortt* pr = &preS[tid * 68];
    float sm = 0.f, qq = 0.f;
    #pragma unroll 8
    for (int c = 0; c < 64; c += 2) {
      u32 u = *(const u32*)&pr[c];
      float v0 = __uint_as_float(u << 16);
      float v1 = __uint_as_float(u & 0xffff0000u);
      sm += v0 + v1; qq += v0 * v0 + v1 * v1;
    }
    float m = sm * (1.f / 64.f);
    mu[tid] = m;
    rs[tid] = rsqrtf(qq * (1.f / 64.f) - m * m + 1e-5f);
  }
  __syncthreads();
  // normalize + affine + store
  #pragma unroll
  for (int ct = 0; ct < 2; ++ct) {
    int s = ct * 16 + l15;
    bool v = (s >= 2 && s <= 25);
    if (!v) continue;
    int p = wave * 24 + s - 2;
    int t = s - 2;
    float m = mu[p], rr = rs[p];
    #pragma unroll
    for (int mt = 0; mt < 4; ++mt) {
      int o0 = mt * 16 + q * 4;
      float4 g4 = *(const float4*)&lg[o0];
      float4 b4 = *(const float4*)&lb[o0];
      float gg[4] = {g4.x, g4.y, g4.z, g4.w};
      float bb[4] = {b4.x, b4.y, b4.z, b4.w};
      #pragma unroll
      for (int r = 0; r < 4; ++r) {
        int o = o0 + r;
        float val = (pre[ct][mt][r] - m) * rr * gg[r] + bb[r];
        outp[((size_t)(b * 64 + o) * 1000 + n0 + wave) * 24 + t] = val;
      }
    }
  }
}

extern "C" void kernel_launch(void* const* d_in, const int* in_sizes, int n_in,
                              void* d_out, int out_size, void* d_ws, size_t ws_size,
                              hipStream_t stream) {
  const float* x     = (const float*)d_in[0];
  const float* Aadj  = (const float*)d_in[1];
  const float* a0W1  = (const float*)d_in[2];
  const float* a0W2  = (const float*)d_in[3];
  const float* gW1   = (const float*)d_in[4];
  const float* gW2   = (const float*)d_in[5];
  const float* gcnW  = (const float*)d_in[6];
  const float* tW1   = (const float*)d_in[7];
  const float* tW2   = (const float*)d_in[8];
  const float* c1w   = (const float*)d_in[9];
  const float* c1b   = (const float*)d_in[10];
  const float* c2w   = (const float*)d_in[11];
  const float* c2b   = (const float*)d_in[12];
  const float* rw    = (const float*)d_in[13];
  const float* rb    = (const float*)d_in[14];
  const float* lng   = (const float*)d_in[15];
  const float* lnb   = (const float*)d_in[16];
  float* out = (float*)d_out;

  float* ws = (float*)d_ws;
  float* R1   = ws;                    // 12,288,000: x1tr -> x2
  float* U    = R1 + 12288000;         // 12,288,000: Xbt+Agb (bf16), later g (f32)
  float* D    = U + 12288000;          // 12,288,000: g1
  float* s1_0 = D + 12288000;          // 5120
  float* s2_0 = s1_0 + 5120;           // 5120
  float* P0   = s2_0 + 5120;           // 32768
  float* s1g  = P0 + 32768;            // 80000
  float* s2gT = s1g + 80000;           // 80000
  float* s1t  = s2gT + 80000;          // 1920
  float* s2t  = s1t + 1920;            // 1920
  float* Ptb  = s2t + 1920;            // 4608
  float* Wp0  = Ptb + 4608;            // 480000
  float* Wgp  = Wp0 + 480000;          // 30720
  float* Wtp  = Wgp + 30720;           // 1280000
  float* Wtl  = Wtp + 1280000;         // 10240 (20480 bf16 packed tail weights)
  ushortt* Xbt = (ushortt*)U;
  ushortt* Agb = (ushortt*)(U + 6291456);
  ushortt* Wtail = (ushortt*)Wtl;
  float* g = U;
  if (ws_size < (size_t)38876416 * 4) return;

  // weight packing
  pack_w<<<1875, 256, 0, stream>>>(a0W1, a0W2, Wp0, 24000);
  pack_w<<<120, 256, 0, stream>>>(gW1, gW2, Wgp, 1536);
  pack_w<<<5000, 256, 0, stream>>>(tW1, tW2, Wtp, 64000);
  pack_tailw<<<80, 256, 0, stream>>>(c1w, c2w, rw, Wtail);
  // stage 1: channel attention
  att0_s12<<<256, 256, 0, stream>>>(x, Wp0, s1_0, s2_0);
  att0_softmax<<<8, 64, 0, stream>>>(s1_0, s2_0, P0);
  att0_apply<<<dim3(250, 8), 256, 0, stream>>>(x, P0, R1);
  // stage 2: gated GCN
  gatt_s12<<<2000, 256, 0, stream>>>(R1, Wgp, s1g, s2gT);
  transpose_x1<<<dim3(24, 16, 8), 256, 0, stream>>>(R1, Xbt);
  gatt_scores<<<8000, 256, 0, stream>>>(s1g, s2gT, Aadj, Agb);
  gemm_mfma<<<dim3(12, 8, 8), 256, 0, stream>>>(Agb, Xbt, D);
  gcn_out<<<dim3(250, 8), 256, 0, stream>>>(D, gcnW, g);
  // stage 3: temporal attention
  zerok<<<15, 256, 0, stream>>>(s1t, 3840);
  tatt_s12<<<dim3(125, 8), 256, 0, stream>>>(g, Wtp, s1t, s2t);
  tatt_softmax<<<8, 32, 0, stream>>>(s1t, s2t, Ptb);
  tatt_apply<<<dim3(250, 8), 256, 0, stream>>>(g, Ptb, R1);
  // stage 4: MFMA tail + residual + LN
  tail_k<<<dim3(250, 8), 256, 0, stream>>>(R1, x, Wtail, c1b, c2b, rb,
                                           lng, lnb, out);
}